// Round 4
// baseline (405.343 us; speedup 1.0000x reference)
//
#include <hip/hip_runtime.h>

// ---------------- fixed problem shape ----------------
#define BATCH  2
#define SEQ    2048
#define DMODEL 1024
#define NHEAD  16
#define HDIM   64
#define NROWS  (BATCH * SEQ)   // 4096
#define QKVC   (3 * DMODEL)    // 3072

typedef float f32x4 __attribute__((ext_vector_type(4)));
typedef short s16x8 __attribute__((ext_vector_type(8)));
typedef short s16x4 __attribute__((ext_vector_type(4)));

__device__ __forceinline__ unsigned short f2bf(float f) {
  unsigned int u = __float_as_uint(f);
  u = (u + 0x7FFFu + ((u >> 16) & 1u)) >> 16;   // RNE
  return (unsigned short)u;
}
__device__ __forceinline__ float bf2f(unsigned short s) {
  return __uint_as_float(((unsigned int)s) << 16);
}

// ---------------------------------------------------------------------------
// 1) row-normalize f32 weight rows (len 1024) -> bf16
// ---------------------------------------------------------------------------
__global__ __launch_bounds__(256) void k_wnorm(const float* __restrict__ W,
                                               unsigned short* __restrict__ Wh) {
  const int row = blockIdx.x, tid = threadIdx.x;
  const float4* rp = (const float4*)(W + (size_t)row * DMODEL);
  float4 v = rp[tid];
  float ss = v.x * v.x + v.y * v.y + v.z * v.z + v.w * v.w;
#pragma unroll
  for (int m = 1; m < 64; m <<= 1) ss += __shfl_xor(ss, m);
  __shared__ float part[4];
  if ((tid & 63) == 0) part[tid >> 6] = ss;
  __syncthreads();
  const float tot = part[0] + part[1] + part[2] + part[3];
  const float scale = 0.03125f / (1e-4f + sqrtf(tot) * 0.03125f);
  unsigned short* op = Wh + (size_t)row * DMODEL + tid * 4;
  op[0] = f2bf(v.x * scale); op[1] = f2bf(v.y * scale);
  op[2] = f2bf(v.z * scale); op[3] = f2bf(v.w * scale);
}

// ---------------------------------------------------------------------------
// 2) f32 -> bf16 cast
// ---------------------------------------------------------------------------
__global__ __launch_bounds__(256) void k_cast(const float* __restrict__ X,
                                              unsigned short* __restrict__ Xb) {
  const int i = blockIdx.x * 256 + threadIdx.x;
  const float4 v = ((const float4*)X)[i];
  ushort4 o = { f2bf(v.x), f2bf(v.y), f2bf(v.z), f2bf(v.w) };
  ((ushort4*)Xb)[i] = o;
}

// ---------------------------------------------------------------------------
// 3) C[M][N] = A[M][K] * B[N][K]^T  (unchanged)
// ---------------------------------------------------------------------------
#define LDP 88
template <int WRITE_BF16>
__global__ __launch_bounds__(256) void k_gemm_bt(const unsigned short* __restrict__ A,
                                                 const unsigned short* __restrict__ Bm,
                                                 void* __restrict__ Cv,
                                                 int M, int N, int K) {
  __shared__ unsigned short As[128 * LDP];
  __shared__ unsigned short Bs[128 * LDP];
  const int tid = threadIdx.x;
  const int nbn = N >> 7;
  const int bm = (blockIdx.x / nbn) << 7;
  const int bn = (blockIdx.x % nbn) << 7;
  const int wave = tid >> 6, lane = tid & 63;
  const int wr = (wave >> 1) << 6, wc = (wave & 1) << 6;
  const int l16 = lane & 15, lg = lane >> 4;

  f32x4 acc[4][4];
#pragma unroll
  for (int m = 0; m < 4; ++m)
#pragma unroll
    for (int n = 0; n < 4; ++n) acc[m][n] = (f32x4){0.f, 0.f, 0.f, 0.f};

  for (int k0 = 0; k0 < K; k0 += 64) {
    s16x8 ra[4], rb[4];
#pragma unroll
    for (int it = 0; it < 4; ++it) {
      const int c = it * 256 + tid;
      const int r = c >> 3, col = (c & 7) << 3;
      ra[it] = *(const s16x8*)(A + (size_t)(bm + r) * K + k0 + col);
      rb[it] = *(const s16x8*)(Bm + (size_t)(bn + r) * K + k0 + col);
    }
    __syncthreads();
#pragma unroll
    for (int it = 0; it < 4; ++it) {
      const int c = it * 256 + tid;
      const int r = c >> 3, col = (c & 7) << 3;
      *(s16x8*)(As + r * LDP + col) = ra[it];
      *(s16x8*)(Bs + r * LDP + col) = rb[it];
    }
    __syncthreads();
#pragma unroll
    for (int ks = 0; ks < 2; ++ks) {
      s16x8 af[4], bq[4];
#pragma unroll
      for (int m = 0; m < 4; ++m)
        af[m] = *(const s16x8*)(As + (wr + m * 16 + l16) * LDP + ks * 32 + lg * 8);
#pragma unroll
      for (int n = 0; n < 4; ++n)
        bq[n] = *(const s16x8*)(Bs + (wc + n * 16 + l16) * LDP + ks * 32 + lg * 8);
#pragma unroll
      for (int m = 0; m < 4; ++m)
#pragma unroll
        for (int n = 0; n < 4; ++n)
          acc[m][n] = __builtin_amdgcn_mfma_f32_16x16x32_bf16(af[m], bq[n], acc[m][n], 0, 0, 0);
    }
  }
  if (WRITE_BF16) {
    unsigned short* C = (unsigned short*)Cv;
#pragma unroll
    for (int m = 0; m < 4; ++m)
#pragma unroll
      for (int n = 0; n < 4; ++n)
#pragma unroll
        for (int r = 0; r < 4; ++r)
          C[(size_t)(bm + wr + m * 16 + lg * 4 + r) * N + (bn + wc + n * 16 + l16)] =
              f2bf(acc[m][n][r]);
  } else {
    float* C = (float*)Cv;
#pragma unroll
    for (int m = 0; m < 4; ++m)
#pragma unroll
      for (int n = 0; n < 4; ++n)
#pragma unroll
        for (int r = 0; r < 4; ++r)
          C[(size_t)(bm + wr + m * 16 + lg * 4 + r) * N + (bn + wc + n * 16 + l16)] =
              acc[m][n][r];
  }
}

// ---------------------------------------------------------------------------
// 4) normalize q,k head-vectors in-place; q rows fold attn scale * log2(e)
// ---------------------------------------------------------------------------
__global__ __launch_bounds__(256) void k_qknorm(unsigned short* __restrict__ qkv) {
  const int row = blockIdx.x, tid = threadIdx.x;
  const int hv = tid >> 3, g = tid & 7;
  const int base = (hv < 16) ? (hv * HDIM) : (DMODEL + (hv - 16) * HDIM);
  unsigned short* p = qkv + (size_t)row * QKVC + base + g * 8;
  s16x8 v = *(const s16x8*)p;
  float f[8];
  float ss = 0.f;
#pragma unroll
  for (int j = 0; j < 8; ++j) { f[j] = bf2f((unsigned short)v[j]); ss += f[j] * f[j]; }
  ss += __shfl_xor(ss, 1); ss += __shfl_xor(ss, 2); ss += __shfl_xor(ss, 4);
  float scale = 1.f / (1e-4f + sqrtf(ss) * 0.125f);
  if (hv < 16) scale *= 0.18033688f;   // (1/sqrt(hd)) * log2(e)
  s16x8 o;
#pragma unroll
  for (int j = 0; j < 8; ++j) o[j] = (short)f2bf(f[j] * scale);
  *(s16x8*)p = o;
}

// ---------------------------------------------------------------------------
// 5) V transpose: qkv v-part -> Vt[bh][d][t]
// ---------------------------------------------------------------------------
__global__ __launch_bounds__(256) void k_vtrans(const unsigned short* __restrict__ qkv,
                                                unsigned short* __restrict__ Vt) {
  const int tt = blockIdx.x & 31, bh = blockIdx.x >> 5;
  const int b = bh >> 4, h = bh & 15;
  const int t0 = tt * 64;
  __shared__ unsigned short tile[64][80];
  const int tid = threadIdx.x;
#pragma unroll
  for (int half = 0; half < 2; ++half) {
    const int tl = half * 32 + (tid >> 3), part = tid & 7;
    s16x8 v = *(const s16x8*)(qkv + (size_t)(b * SEQ + t0 + tl) * QKVC + 2 * DMODEL +
                              h * HDIM + part * 8);
    *(s16x8*)(&tile[tl][part * 8]) = v;
  }
  __syncthreads();
#pragma unroll
  for (int half = 0; half < 2; ++half) {
    const int d = half * 32 + (tid >> 3), tp = tid & 7;
    s16x8 o;
#pragma unroll
    for (int j = 0; j < 8; ++j) o[j] = (short)tile[tp * 8 + j][d];
    *(s16x8*)(Vt + (size_t)(bh * HDIM + d) * SEQ + t0 + tp * 8) = o;
  }
}

// ---------------------------------------------------------------------------
// 6) shared attention machinery (swapped-operand, KB=32, exp2 softmax)
//    NOLOAD=0: real kernel, loads pipelined + sched_barrier(0) pins.
//    NOLOAD=1: diagnostic — K/V loaded once pre-loop, re-fed via asm "+v"
//              each iter (defeats LICM, keeps all downstream work live).
// ---------------------------------------------------------------------------
#define PST 36
template <int NOLOAD>
__global__ __launch_bounds__(256) void k_attn_t(const unsigned short* __restrict__ qkv,
                                                const unsigned short* __restrict__ Vt,
                                                unsigned short* __restrict__ O) {
  const int qt = blockIdx.x & 31, bh = blockIdx.x >> 5;
  const int b = bh >> 4, h = bh & 15;
  const int wave = threadIdx.x >> 6, lane = threadIdx.x & 63;
  const int l16 = lane & 15, lg = lane >> 4;
  const int q0 = qt * 64 + wave * 16;

  __shared__ unsigned short P[4][16 * PST];
  unsigned short* Pw = &P[wave][0];

  const size_t qbase = (size_t)(b * SEQ + q0 + l16) * QKVC + h * HDIM;
  const s16x8 aq0 = *(const s16x8*)(qkv + qbase + lg * 8);
  const s16x8 aq1 = *(const s16x8*)(qkv + qbase + 32 + lg * 8);

  const unsigned short* kbase0 =
      qkv + (size_t)(b * SEQ + l16) * QKVC + DMODEL + h * HDIM + lg * 8;
  const unsigned short* vbase0 = Vt + (size_t)(bh * HDIM + l16) * SEQ + lg * 8;

  f32x4 o[4];
#pragma unroll
  for (int n = 0; n < 4; ++n) o[n] = (f32x4){0.f, 0.f, 0.f, 0.f};
  float m = -1e30f, l = 0.f;

#define LOADK(KT, K00, K01, K10, K11) {                                   \
    const unsigned short* kp = kbase0 + (size_t)(KT) * QKVC;              \
    K00 = *(const s16x8*)(kp);                                            \
    K01 = *(const s16x8*)(kp + 32);                                       \
    K10 = *(const s16x8*)(kp + 16 * QKVC);                                \
    K11 = *(const s16x8*)(kp + 16 * QKVC + 32); }

#define LOADV(KT, V0, V1, V2, V3) {                                       \
    const unsigned short* vp = vbase0 + (KT);                             \
    V0 = *(const s16x8*)(vp);                                             \
    V1 = *(const s16x8*)(vp + 16 * SEQ);                                  \
    V2 = *(const s16x8*)(vp + 32 * SEQ);                                  \
    V3 = *(const s16x8*)(vp + 48 * SEQ); }

#define COMPUTE(K00, K01, K10, K11, V0, V1, V2, V3) {                     \
    f32x4 s0 = (f32x4){0.f, 0.f, 0.f, 0.f}, s1 = s0;                     \
    __builtin_amdgcn_s_setprio(1);                                        \
    s0 = __builtin_amdgcn_mfma_f32_16x16x32_bf16(K00, aq0, s0, 0, 0, 0);  \
    s0 = __builtin_amdgcn_mfma_f32_16x16x32_bf16(K01, aq1, s0, 0, 0, 0);  \
    s1 = __builtin_amdgcn_mfma_f32_16x16x32_bf16(K10, aq0, s1, 0, 0, 0);  \
    s1 = __builtin_amdgcn_mfma_f32_16x16x32_bf16(K11, aq1, s1, 0, 0, 0);  \
    __builtin_amdgcn_s_setprio(0);                                        \
    float tm = fmaxf(fmaxf(fmaxf(s0[0], s0[1]), fmaxf(s0[2], s0[3])),     \
                     fmaxf(fmaxf(s1[0], s1[1]), fmaxf(s1[2], s1[3])));    \
    tm = fmaxf(tm, __shfl_xor(tm, 16));                                   \
    tm = fmaxf(tm, __shfl_xor(tm, 32));                                   \
    const float mnew = fmaxf(m, tm);                                      \
    const float c = exp2f(m - mnew);                                      \
    m = mnew;                                                             \
    float rs = 0.f;                                                       \
    _Pragma("unroll") for (int r = 0; r < 4; ++r) {                       \
      s0[r] = exp2f(s0[r] - mnew); rs += s0[r];                           \
      s1[r] = exp2f(s1[r] - mnew); rs += s1[r];                           \
    }                                                                     \
    rs += __shfl_xor(rs, 16);                                             \
    rs += __shfl_xor(rs, 32);                                             \
    l = l * c + rs;                                                       \
    o[0] *= c; o[1] *= c; o[2] *= c; o[3] *= c;                           \
    s16x4 p0 = { (short)f2bf(s0[0]), (short)f2bf(s0[1]),                  \
                 (short)f2bf(s0[2]), (short)f2bf(s0[3]) };                \
    s16x4 p1 = { (short)f2bf(s1[0]), (short)f2bf(s1[1]),                  \
                 (short)f2bf(s1[2]), (short)f2bf(s1[3]) };                \
    *(s16x4*)(Pw + l16 * PST + lg * 4) = p0;                              \
    *(s16x4*)(Pw + l16 * PST + 16 + lg * 4) = p1;                         \
    const s16x8 pa = *(const s16x8*)(Pw + l16 * PST + lg * 8);            \
    __builtin_amdgcn_s_setprio(1);                                        \
    o[0] = __builtin_amdgcn_mfma_f32_16x16x32_bf16(V0, pa, o[0], 0, 0, 0);\
    o[1] = __builtin_amdgcn_mfma_f32_16x16x32_bf16(V1, pa, o[1], 0, 0, 0);\
    o[2] = __builtin_amdgcn_mfma_f32_16x16x32_bf16(V2, pa, o[2], 0, 0, 0);\
    o[3] = __builtin_amdgcn_mfma_f32_16x16x32_bf16(V3, pa, o[3], 0, 0, 0);\
    __builtin_amdgcn_s_setprio(0); }

  s16x8 kA00, kA01, kA10, kA11, vA0, vA1, vA2, vA3;
  LOADK(0, kA00, kA01, kA10, kA11);
  LOADV(0, vA0, vA1, vA2, vA3);

  if (NOLOAD) {
    // diagnostic: no global loads in the loop; "+v" re-feed defeats LICM
    for (int kt = 0; kt < SEQ; kt += 32) {
      asm volatile("" : "+v"(kA00), "+v"(kA01), "+v"(kA10), "+v"(kA11));
      asm volatile("" : "+v"(vA0), "+v"(vA1), "+v"(vA2), "+v"(vA3));
      COMPUTE(kA00, kA01, kA10, kA11, vA0, vA1, vA2, vA3);
    }
  } else {
    s16x8 kB00, kB01, kB10, kB11, vB0, vB1, vB2, vB3;
    for (int kt = 0; kt < SEQ; kt += 64) {
      LOADK(kt + 32, kB00, kB01, kB10, kB11);
      LOADV(kt + 32, vB0, vB1, vB2, vB3);
      __builtin_amdgcn_sched_barrier(0);   // B-loads must issue before COMPUTE(A)
      COMPUTE(kA00, kA01, kA10, kA11, vA0, vA1, vA2, vA3);
      __builtin_amdgcn_sched_barrier(0);
      if (kt + 64 < SEQ) {
        LOADK(kt + 64, kA00, kA01, kA10, kA11);
        LOADV(kt + 64, vA0, vA1, vA2, vA3);
      }
      __builtin_amdgcn_sched_barrier(0);   // A-loads must issue before COMPUTE(B)
      COMPUTE(kB00, kB01, kB10, kB11, vB0, vB1, vB2, vB3);
      __builtin_amdgcn_sched_barrier(0);
    }
  }
#undef LOADK
#undef LOADV
#undef COMPUTE

  const float inv = 1.f / l;
#pragma unroll
  for (int n = 0; n < 4; ++n) {
    s16x4 ov = { (short)f2bf(o[n][0] * inv), (short)f2bf(o[n][1] * inv),
                 (short)f2bf(o[n][2] * inv), (short)f2bf(o[n][3] * inv) };
    *(s16x4*)(O + (size_t)(b * SEQ + q0 + l16) * DMODEL + h * HDIM + n * 16 + lg * 4) = ov;
  }
}

// ---------------------------------------------------------------------------
// launch: ws layout (bytes): Wq[0,6M) Wo[6M,8M) Xb[8M,16M) QKV[16M,40M) Vt[40M,48M)
// k_attn_t<1> (diagnostic) writes garbage into Xb; k_attn_t<0> then fully
// overwrites every byte of the O region -> output remains correct.
// ---------------------------------------------------------------------------
extern "C" void kernel_launch(void* const* d_in, const int* in_sizes, int n_in,
                              void* d_out, int out_size, void* d_ws, size_t ws_size,
                              hipStream_t stream) {
  const float* x    = (const float*)d_in[0];
  const float* wqkv = (const float*)d_in[1];
  const float* wout = (const float*)d_in[2];
  char* ws = (char*)d_ws;
  unsigned short* Wq  = (unsigned short*)(ws);
  unsigned short* Wo  = (unsigned short*)(ws + 6291456);
  unsigned short* Xb  = (unsigned short*)(ws + 8388608);
  unsigned short* QKV = (unsigned short*)(ws + 16777216);
  unsigned short* Vt  = (unsigned short*)(ws + 41943040);
  (void)in_sizes; (void)n_in; (void)out_size; (void)ws_size;

  k_wnorm<<<QKVC, 256, 0, stream>>>(wqkv, Wq);
  k_wnorm<<<DMODEL, 256, 0, stream>>>(wout, Wo);
  k_cast<<<(NROWS * DMODEL) / 1024, 256, 0, stream>>>(x, Xb);
  k_gemm_bt<1><<<(NROWS / 128) * (QKVC / 128), 256, 0, stream>>>(
      Xb, Wq, (void*)QKV, NROWS, QKVC, DMODEL);
  k_qknorm<<<NROWS, 256, 0, stream>>>(QKV);
  k_vtrans<<<BATCH * NHEAD * (SEQ / 64), 256, 0, stream>>>(QKV, Vt);
  k_attn_t<1><<<BATCH * NHEAD * (SEQ / 64), 256, 0, stream>>>(QKV, Vt, Xb);  // diagnostic
  k_attn_t<0><<<BATCH * NHEAD * (SEQ / 64), 256, 0, stream>>>(QKV, Vt, Xb);  // real
  k_gemm_bt<0><<<(NROWS / 128) * (DMODEL / 128), 256, 0, stream>>>(
      Xb, Wo, d_out, NROWS, DMODEL, DMODEL);
}

// Round 5
// 318.311 us; speedup vs baseline: 1.2734x; 1.2734x over previous
//
#include <hip/hip_runtime.h>

// ---------------- fixed problem shape ----------------
#define BATCH  2
#define SEQ    2048
#define DMODEL 1024
#define NHEAD  16
#define HDIM   64
#define NROWS  (BATCH * SEQ)   // 4096
#define QKVC   (3 * DMODEL)    // 3072

typedef float f32x4 __attribute__((ext_vector_type(4)));
typedef short s16x8 __attribute__((ext_vector_type(8)));
typedef short s16x4 __attribute__((ext_vector_type(4)));

__device__ __forceinline__ unsigned short f2bf(float f) {
  unsigned int u = __float_as_uint(f);
  u = (u + 0x7FFFu + ((u >> 16) & 1u)) >> 16;   // RNE
  return (unsigned short)u;
}
__device__ __forceinline__ float bf2f(unsigned short s) {
  return __uint_as_float(((unsigned int)s) << 16);
}

// ---------------------------------------------------------------------------
// 1) row-normalize f32 weight rows (len 1024) -> bf16
// ---------------------------------------------------------------------------
__global__ __launch_bounds__(256) void k_wnorm(const float* __restrict__ W,
                                               unsigned short* __restrict__ Wh) {
  const int row = blockIdx.x, tid = threadIdx.x;
  const float4* rp = (const float4*)(W + (size_t)row * DMODEL);
  float4 v = rp[tid];
  float ss = v.x * v.x + v.y * v.y + v.z * v.z + v.w * v.w;
#pragma unroll
  for (int m = 1; m < 64; m <<= 1) ss += __shfl_xor(ss, m);
  __shared__ float part[4];
  if ((tid & 63) == 0) part[tid >> 6] = ss;
  __syncthreads();
  const float tot = part[0] + part[1] + part[2] + part[3];
  const float scale = 0.03125f / (1e-4f + sqrtf(tot) * 0.03125f);
  unsigned short* op = Wh + (size_t)row * DMODEL + tid * 4;
  op[0] = f2bf(v.x * scale); op[1] = f2bf(v.y * scale);
  op[2] = f2bf(v.z * scale); op[3] = f2bf(v.w * scale);
}

// ---------------------------------------------------------------------------
// 2) f32 -> bf16 cast
// ---------------------------------------------------------------------------
__global__ __launch_bounds__(256) void k_cast(const float* __restrict__ X,
                                              unsigned short* __restrict__ Xb) {
  const int i = blockIdx.x * 256 + threadIdx.x;
  const float4 v = ((const float4*)X)[i];
  ushort4 o = { f2bf(v.x), f2bf(v.y), f2bf(v.z), f2bf(v.w) };
  ((ushort4*)Xb)[i] = o;
}

// ---------------------------------------------------------------------------
// 3) C[M][N] = A[M][K] * B[N][K]^T  (unchanged)
// ---------------------------------------------------------------------------
#define LDP 88
template <int WRITE_BF16>
__global__ __launch_bounds__(256) void k_gemm_bt(const unsigned short* __restrict__ A,
                                                 const unsigned short* __restrict__ Bm,
                                                 void* __restrict__ Cv,
                                                 int M, int N, int K) {
  __shared__ unsigned short As[128 * LDP];
  __shared__ unsigned short Bs[128 * LDP];
  const int tid = threadIdx.x;
  const int nbn = N >> 7;
  const int bm = (blockIdx.x / nbn) << 7;
  const int bn = (blockIdx.x % nbn) << 7;
  const int wave = tid >> 6, lane = tid & 63;
  const int wr = (wave >> 1) << 6, wc = (wave & 1) << 6;
  const int l16 = lane & 15, lg = lane >> 4;

  f32x4 acc[4][4];
#pragma unroll
  for (int m = 0; m < 4; ++m)
#pragma unroll
    for (int n = 0; n < 4; ++n) acc[m][n] = (f32x4){0.f, 0.f, 0.f, 0.f};

  for (int k0 = 0; k0 < K; k0 += 64) {
    s16x8 ra[4], rb[4];
#pragma unroll
    for (int it = 0; it < 4; ++it) {
      const int c = it * 256 + tid;
      const int r = c >> 3, col = (c & 7) << 3;
      ra[it] = *(const s16x8*)(A + (size_t)(bm + r) * K + k0 + col);
      rb[it] = *(const s16x8*)(Bm + (size_t)(bn + r) * K + k0 + col);
    }
    __syncthreads();
#pragma unroll
    for (int it = 0; it < 4; ++it) {
      const int c = it * 256 + tid;
      const int r = c >> 3, col = (c & 7) << 3;
      *(s16x8*)(As + r * LDP + col) = ra[it];
      *(s16x8*)(Bs + r * LDP + col) = rb[it];
    }
    __syncthreads();
#pragma unroll
    for (int ks = 0; ks < 2; ++ks) {
      s16x8 af[4], bq[4];
#pragma unroll
      for (int m = 0; m < 4; ++m)
        af[m] = *(const s16x8*)(As + (wr + m * 16 + l16) * LDP + ks * 32 + lg * 8);
#pragma unroll
      for (int n = 0; n < 4; ++n)
        bq[n] = *(const s16x8*)(Bs + (wc + n * 16 + l16) * LDP + ks * 32 + lg * 8);
#pragma unroll
      for (int m = 0; m < 4; ++m)
#pragma unroll
        for (int n = 0; n < 4; ++n)
          acc[m][n] = __builtin_amdgcn_mfma_f32_16x16x32_bf16(af[m], bq[n], acc[m][n], 0, 0, 0);
    }
  }
  if (WRITE_BF16) {
    unsigned short* C = (unsigned short*)Cv;
#pragma unroll
    for (int m = 0; m < 4; ++m)
#pragma unroll
      for (int n = 0; n < 4; ++n)
#pragma unroll
        for (int r = 0; r < 4; ++r)
          C[(size_t)(bm + wr + m * 16 + lg * 4 + r) * N + (bn + wc + n * 16 + l16)] =
              f2bf(acc[m][n][r]);
  } else {
    float* C = (float*)Cv;
#pragma unroll
    for (int m = 0; m < 4; ++m)
#pragma unroll
      for (int n = 0; n < 4; ++n)
#pragma unroll
        for (int r = 0; r < 4; ++r)
          C[(size_t)(bm + wr + m * 16 + lg * 4 + r) * N + (bn + wc + n * 16 + l16)] =
              acc[m][n][r];
  }
}

// ---------------------------------------------------------------------------
// 4) normalize q,k head-vectors in-place; q rows fold attn scale 1/8 only
//    (back to natural-exp domain: __expf = v_mul + v_exp_f32)
// ---------------------------------------------------------------------------
__global__ __launch_bounds__(256) void k_qknorm(unsigned short* __restrict__ qkv) {
  const int row = blockIdx.x, tid = threadIdx.x;
  const int hv = tid >> 3, g = tid & 7;
  const int base = (hv < 16) ? (hv * HDIM) : (DMODEL + (hv - 16) * HDIM);
  unsigned short* p = qkv + (size_t)row * QKVC + base + g * 8;
  s16x8 v = *(const s16x8*)p;
  float f[8];
  float ss = 0.f;
#pragma unroll
  for (int j = 0; j < 8; ++j) { f[j] = bf2f((unsigned short)v[j]); ss += f[j] * f[j]; }
  ss += __shfl_xor(ss, 1); ss += __shfl_xor(ss, 2); ss += __shfl_xor(ss, 4);
  float scale = 1.f / (1e-4f + sqrtf(ss) * 0.125f);
  if (hv < 16) scale *= 0.125f;           // fold attn 1/sqrt(hd)
  s16x8 o;
#pragma unroll
  for (int j = 0; j < 8; ++j) o[j] = (short)f2bf(f[j] * scale);
  *(s16x8*)p = o;
}

// ---------------------------------------------------------------------------
// 5) V transpose: qkv v-part -> Vt[bh][d][t]
// ---------------------------------------------------------------------------
__global__ __launch_bounds__(256) void k_vtrans(const unsigned short* __restrict__ qkv,
                                                unsigned short* __restrict__ Vt) {
  const int tt = blockIdx.x & 31, bh = blockIdx.x >> 5;
  const int b = bh >> 4, h = bh & 15;
  const int t0 = tt * 64;
  __shared__ unsigned short tile[64][80];
  const int tid = threadIdx.x;
#pragma unroll
  for (int half = 0; half < 2; ++half) {
    const int tl = half * 32 + (tid >> 3), part = tid & 7;
    s16x8 v = *(const s16x8*)(qkv + (size_t)(b * SEQ + t0 + tl) * QKVC + 2 * DMODEL +
                              h * HDIM + part * 8);
    *(s16x8*)(&tile[tl][part * 8]) = v;
  }
  __syncthreads();
#pragma unroll
  for (int half = 0; half < 2; ++half) {
    const int d = half * 32 + (tid >> 3), tp = tid & 7;
    s16x8 o;
#pragma unroll
    for (int j = 0; j < 8; ++j) o[j] = (short)tile[tp * 8 + j][d];
    *(s16x8*)(Vt + (size_t)(bh * HDIM + d) * SEQ + t0 + tp * 8) = o;
  }
}

// ---------------------------------------------------------------------------
// 6) flash attention, KEY-SPLIT x2: 512 threads / 8 waves. Waves qw and qw+4
//    process the same 16 queries over disjoint key halves (1024 each, KB=64),
//    then merge (m, l, O) through LDS. Doubles resident waves (latency hiding)
//    and halves each wave's serial chain. Swapped-operand QK^T as before.
// ---------------------------------------------------------------------------
#define PST 72
__global__ __launch_bounds__(512) void k_attn(const unsigned short* __restrict__ qkv,
                                              const unsigned short* __restrict__ Vt,
                                              unsigned short* __restrict__ O) {
  const int qt = blockIdx.x & 31, bh = blockIdx.x >> 5;
  const int b = bh >> 4, h = bh & 15;
  const int wave = threadIdx.x >> 6, lane = threadIdx.x & 63;
  const int l16 = lane & 15, lg = lane >> 4;
  const int qw = wave & 3, half = wave >> 2;
  const int q0 = qt * 64 + qw * 16;
  const int k0base = half * (SEQ / 2);

  __shared__ unsigned short P[8][16 * PST];
  __shared__ f32x4 OO[4][4][64];
  __shared__ float MM[4][16], LL[4][16];
  unsigned short* Pw = &P[wave][0];

  // Q fragments (B operand: col=q=l16, k=8*lg+j); 1/8 scale pre-folded
  const size_t qbase = (size_t)(b * SEQ + q0 + l16) * QKVC + h * HDIM;
  const s16x8 aq0 = *(const s16x8*)(qkv + qbase + lg * 8);
  const s16x8 aq1 = *(const s16x8*)(qkv + qbase + 32 + lg * 8);

  f32x4 o[4];
#pragma unroll
  for (int n = 0; n < 4; ++n) o[n] = (f32x4){0.f, 0.f, 0.f, 0.f};
  float m = -1e30f, l = 0.f;

  for (int kt = k0base; kt < k0base + SEQ / 2; kt += 64) {
    // ---- S^T = K * Q^T  (rows = keys, cols = queries) ----
    f32x4 st[4];
    __builtin_amdgcn_s_setprio(1);
#pragma unroll
    for (int sub = 0; sub < 4; ++sub) {
      const size_t kbase =
          (size_t)(b * SEQ + kt + sub * 16 + l16) * QKVC + DMODEL + h * HDIM;
      const s16x8 bk0 = *(const s16x8*)(qkv + kbase + lg * 8);
      const s16x8 bk1 = *(const s16x8*)(qkv + kbase + 32 + lg * 8);
      f32x4 z = (f32x4){0.f, 0.f, 0.f, 0.f};
      z = __builtin_amdgcn_mfma_f32_16x16x32_bf16(bk0, aq0, z, 0, 0, 0);
      z = __builtin_amdgcn_mfma_f32_16x16x32_bf16(bk1, aq1, z, 0, 0, 0);
      st[sub] = z;
    }
    __builtin_amdgcn_s_setprio(0);
    // ---- prefetch V fragments for this key tile ----
    s16x8 bv0[4], bv1[4];
#pragma unroll
    for (int n = 0; n < 4; ++n) {
      const size_t vbase = (size_t)(bh * HDIM + n * 16 + l16) * SEQ + kt;
      bv0[n] = *(const s16x8*)(Vt + vbase + lg * 8);
      bv1[n] = *(const s16x8*)(Vt + vbase + 32 + lg * 8);
    }
    // ---- online softmax: all 16 values in-lane belong to q = l16 ----
    float tm = fmaxf(fmaxf(fmaxf(st[0][0], st[0][1]), fmaxf(st[0][2], st[0][3])),
                     fmaxf(fmaxf(st[1][0], st[1][1]), fmaxf(st[1][2], st[1][3])));
    tm = fmaxf(tm, fmaxf(fmaxf(fmaxf(st[2][0], st[2][1]), fmaxf(st[2][2], st[2][3])),
                         fmaxf(fmaxf(st[3][0], st[3][1]), fmaxf(st[3][2], st[3][3]))));
    tm = fmaxf(tm, __shfl_xor(tm, 16));
    tm = fmaxf(tm, __shfl_xor(tm, 32));
    const float mnew = fmaxf(m, tm);
    const float c = __expf(m - mnew);
    m = mnew;
    float rs = 0.f;
#pragma unroll
    for (int sub = 0; sub < 4; ++sub)
#pragma unroll
      for (int r = 0; r < 4; ++r) {
        const float pv = __expf(st[sub][r] - mnew);
        st[sub][r] = pv;
        rs += pv;
      }
    rs += __shfl_xor(rs, 16);
    rs += __shfl_xor(rs, 32);
    l = l * c + rs;
#pragma unroll
    for (int n = 0; n < 4; ++n) o[n] *= c;
    // ---- P^T -> LDS [q][key], read back as B-frags ----
#pragma unroll
    for (int sub = 0; sub < 4; ++sub) {
      s16x4 pk = { (short)f2bf(st[sub][0]), (short)f2bf(st[sub][1]),
                   (short)f2bf(st[sub][2]), (short)f2bf(st[sub][3]) };
      *(s16x4*)(Pw + l16 * PST + sub * 16 + lg * 4) = pk;
    }
    const s16x8 pa0 = *(const s16x8*)(Pw + l16 * PST + lg * 8);
    const s16x8 pa1 = *(const s16x8*)(Pw + l16 * PST + 32 + lg * 8);
    // ---- O^T += V^T * P^T ----
    __builtin_amdgcn_s_setprio(1);
#pragma unroll
    for (int n = 0; n < 4; ++n) {
      o[n] = __builtin_amdgcn_mfma_f32_16x16x32_bf16(bv0[n], pa0, o[n], 0, 0, 0);
      o[n] = __builtin_amdgcn_mfma_f32_16x16x32_bf16(bv1[n], pa1, o[n], 0, 0, 0);
    }
    __builtin_amdgcn_s_setprio(0);
  }

  // ---- cross-half merge: waves 4-7 publish, waves 0-3 combine + write ----
  if (wave >= 4) {
#pragma unroll
    for (int n = 0; n < 4; ++n) OO[qw][n][lane] = o[n];
    if (lg == 0) { MM[qw][l16] = m; LL[qw][l16] = l; }
  }
  __syncthreads();
  if (wave < 4) {
    const float m2 = MM[qw][l16], l2 = LL[qw][l16];
    const float M = fmaxf(m, m2);
    const float c1 = __expf(m - M), c2 = __expf(m2 - M);
    const float inv = 1.f / (l * c1 + l2 * c2);
#pragma unroll
    for (int n = 0; n < 4; ++n) {
      const f32x4 om = o[n] * c1 + OO[qw][n][lane] * c2;
      s16x4 ov = { (short)f2bf(om[0] * inv), (short)f2bf(om[1] * inv),
                   (short)f2bf(om[2] * inv), (short)f2bf(om[3] * inv) };
      *(s16x4*)(O + (size_t)(b * SEQ + q0 + l16) * DMODEL + h * HDIM + n * 16 + lg * 4) = ov;
    }
  }
}

// ---------------------------------------------------------------------------
// launch: ws layout (bytes): Wq[0,6M) Wo[6M,8M) Xb[8M,16M) QKV[16M,40M) Vt[40M,48M)
// ---------------------------------------------------------------------------
extern "C" void kernel_launch(void* const* d_in, const int* in_sizes, int n_in,
                              void* d_out, int out_size, void* d_ws, size_t ws_size,
                              hipStream_t stream) {
  const float* x    = (const float*)d_in[0];
  const float* wqkv = (const float*)d_in[1];
  const float* wout = (const float*)d_in[2];
  char* ws = (char*)d_ws;
  unsigned short* Wq  = (unsigned short*)(ws);
  unsigned short* Wo  = (unsigned short*)(ws + 6291456);
  unsigned short* Xb  = (unsigned short*)(ws + 8388608);
  unsigned short* QKV = (unsigned short*)(ws + 16777216);
  unsigned short* Vt  = (unsigned short*)(ws + 41943040);
  (void)in_sizes; (void)n_in; (void)out_size; (void)ws_size;

  k_wnorm<<<QKVC, 256, 0, stream>>>(wqkv, Wq);
  k_wnorm<<<DMODEL, 256, 0, stream>>>(wout, Wo);
  k_cast<<<(NROWS * DMODEL) / 1024, 256, 0, stream>>>(x, Xb);
  k_gemm_bt<1><<<(NROWS / 128) * (QKVC / 128), 256, 0, stream>>>(
      Xb, Wq, (void*)QKV, NROWS, QKVC, DMODEL);
  k_qknorm<<<NROWS, 256, 0, stream>>>(QKV);
  k_vtrans<<<BATCH * NHEAD * (SEQ / 64), 256, 0, stream>>>(QKV, Vt);
  k_attn<<<BATCH * NHEAD * (SEQ / 64), 512, 0, stream>>>(QKV, Vt, Xb);
  k_gemm_bt<0><<<(NROWS / 128) * (DMODEL / 128), 256, 0, stream>>>(
      Xb, Wo, d_out, NROWS, DMODEL, DMODEL);
}

// Round 8
// 212.235 us; speedup vs baseline: 1.9099x; 1.4998x over previous
//
#include <hip/hip_runtime.h>

// ---------------- fixed problem shape ----------------
#define BATCH  2
#define SEQ    2048
#define DMODEL 1024
#define NHEAD  16
#define HDIM   64
#define NROWS  (BATCH * SEQ)   // 4096
#define QKVC   (3 * DMODEL)    // 3072

typedef float f32x4 __attribute__((ext_vector_type(4)));
typedef float f32x16 __attribute__((ext_vector_type(16)));
typedef short s16x8 __attribute__((ext_vector_type(8)));
typedef short s16x4 __attribute__((ext_vector_type(4)));
typedef unsigned int u32x4 __attribute__((ext_vector_type(4)));

__device__ __forceinline__ unsigned short f2bf(float f) {
  unsigned int u = __float_as_uint(f);
  u = (u + 0x7FFFu + ((u >> 16) & 1u)) >> 16;   // RNE
  return (unsigned short)u;
}
__device__ __forceinline__ float bf2f(unsigned short s) {
  return __uint_as_float(((unsigned int)s) << 16);
}
// pack two f32 -> two bf16 in one u32 (low = a, high = b)
__device__ __forceinline__ unsigned pkbf(float a, float b) {
  unsigned r;
  asm("v_cvt_pk_bf16_f32 %0, %1, %2" : "=v"(r) : "v"(a), "v"(b));
  return r;
}
// v_permlane32_swap_b32 DST, SRC: DST[32:63] <-> SRC[0:31]
// (semantics cross-validated: the m214 cvt_pk+swap recipe only lands all
//  fragment words correctly under this direction)
__device__ __forceinline__ void swp(unsigned &a, unsigned &b) {
  asm volatile("v_permlane32_swap_b32 %0, %1" : "+v"(a), "+v"(b));
}

// ---------------------------------------------------------------------------
// 1) row-normalize f32 weight rows (len 1024) -> bf16
// ---------------------------------------------------------------------------
__global__ __launch_bounds__(256) void k_wnorm(const float* __restrict__ W,
                                               unsigned short* __restrict__ Wh) {
  const int row = blockIdx.x, tid = threadIdx.x;
  const float4* rp = (const float4*)(W + (size_t)row * DMODEL);
  float4 v = rp[tid];
  float ss = v.x * v.x + v.y * v.y + v.z * v.z + v.w * v.w;
#pragma unroll
  for (int m = 1; m < 64; m <<= 1) ss += __shfl_xor(ss, m);
  __shared__ float part[4];
  if ((tid & 63) == 0) part[tid >> 6] = ss;
  __syncthreads();
  const float tot = part[0] + part[1] + part[2] + part[3];
  const float scale = 0.03125f / (1e-4f + sqrtf(tot) * 0.03125f);
  unsigned short* op = Wh + (size_t)row * DMODEL + tid * 4;
  op[0] = f2bf(v.x * scale); op[1] = f2bf(v.y * scale);
  op[2] = f2bf(v.z * scale); op[3] = f2bf(v.w * scale);
}

// ---------------------------------------------------------------------------
// 2) f32 -> bf16 cast
// ---------------------------------------------------------------------------
__global__ __launch_bounds__(256) void k_cast(const float* __restrict__ X,
                                              unsigned short* __restrict__ Xb) {
  const int i = blockIdx.x * 256 + threadIdx.x;
  const float4 v = ((const float4*)X)[i];
  ushort4 o = { f2bf(v.x), f2bf(v.y), f2bf(v.z), f2bf(v.w) };
  ((ushort4*)Xb)[i] = o;
}

// ---------------------------------------------------------------------------
// 3) C[M][N] = A[M][K] * B[N][K]^T  (unchanged)
// ---------------------------------------------------------------------------
#define LDP 88
template <int WRITE_BF16>
__global__ __launch_bounds__(256) void k_gemm_bt(const unsigned short* __restrict__ A,
                                                 const unsigned short* __restrict__ Bm,
                                                 void* __restrict__ Cv,
                                                 int M, int N, int K) {
  __shared__ unsigned short As[128 * LDP];
  __shared__ unsigned short Bs[128 * LDP];
  const int tid = threadIdx.x;
  const int nbn = N >> 7;
  const int bm = (blockIdx.x / nbn) << 7;
  const int bn = (blockIdx.x % nbn) << 7;
  const int wave = tid >> 6, lane = tid & 63;
  const int wr = (wave >> 1) << 6, wc = (wave & 1) << 6;
  const int l16 = lane & 15, lg = lane >> 4;

  f32x4 acc[4][4];
#pragma unroll
  for (int m = 0; m < 4; ++m)
#pragma unroll
    for (int n = 0; n < 4; ++n) acc[m][n] = (f32x4){0.f, 0.f, 0.f, 0.f};

  for (int k0 = 0; k0 < K; k0 += 64) {
    s16x8 ra[4], rb[4];
#pragma unroll
    for (int it = 0; it < 4; ++it) {
      const int c = it * 256 + tid;
      const int r = c >> 3, col = (c & 7) << 3;
      ra[it] = *(const s16x8*)(A + (size_t)(bm + r) * K + k0 + col);
      rb[it] = *(const s16x8*)(Bm + (size_t)(bn + r) * K + k0 + col);
    }
    __syncthreads();
#pragma unroll
    for (int it = 0; it < 4; ++it) {
      const int c = it * 256 + tid;
      const int r = c >> 3, col = (c & 7) << 3;
      *(s16x8*)(As + r * LDP + col) = ra[it];
      *(s16x8*)(Bs + r * LDP + col) = rb[it];
    }
    __syncthreads();
#pragma unroll
    for (int ks = 0; ks < 2; ++ks) {
      s16x8 af[4], bq[4];
#pragma unroll
      for (int m = 0; m < 4; ++m)
        af[m] = *(const s16x8*)(As + (wr + m * 16 + l16) * LDP + ks * 32 + lg * 8);
#pragma unroll
      for (int n = 0; n < 4; ++n)
        bq[n] = *(const s16x8*)(Bs + (wc + n * 16 + l16) * LDP + ks * 32 + lg * 8);
#pragma unroll
      for (int m = 0; m < 4; ++m)
#pragma unroll
        for (int n = 0; n < 4; ++n)
          acc[m][n] = __builtin_amdgcn_mfma_f32_16x16x32_bf16(af[m], bq[n], acc[m][n], 0, 0, 0);
    }
  }
  if (WRITE_BF16) {
    unsigned short* C = (unsigned short*)Cv;
#pragma unroll
    for (int m = 0; m < 4; ++m)
#pragma unroll
      for (int n = 0; n < 4; ++n)
#pragma unroll
        for (int r = 0; r < 4; ++r)
          C[(size_t)(bm + wr + m * 16 + lg * 4 + r) * N + (bn + wc + n * 16 + l16)] =
              f2bf(acc[m][n][r]);
  } else {
    float* C = (float*)Cv;
#pragma unroll
    for (int m = 0; m < 4; ++m)
#pragma unroll
      for (int n = 0; n < 4; ++n)
#pragma unroll
        for (int r = 0; r < 4; ++r)
          C[(size_t)(bm + wr + m * 16 + lg * 4 + r) * N + (bn + wc + n * 16 + l16)] =
              acc[m][n][r];
  }
}

// ---------------------------------------------------------------------------
// 4) normalize q,k head-vectors in-place; q rows fold attn scale 1/8
// ---------------------------------------------------------------------------
__global__ __launch_bounds__(256) void k_qknorm(unsigned short* __restrict__ qkv) {
  const int row = blockIdx.x, tid = threadIdx.x;
  const int hv = tid >> 3, g = tid & 7;
  const int base = (hv < 16) ? (hv * HDIM) : (DMODEL + (hv - 16) * HDIM);
  unsigned short* p = qkv + (size_t)row * QKVC + base + g * 8;
  s16x8 v = *(const s16x8*)p;
  float f[8];
  float ss = 0.f;
#pragma unroll
  for (int j = 0; j < 8; ++j) { f[j] = bf2f((unsigned short)v[j]); ss += f[j] * f[j]; }
  ss += __shfl_xor(ss, 1); ss += __shfl_xor(ss, 2); ss += __shfl_xor(ss, 4);
  float scale = 1.f / (1e-4f + sqrtf(ss) * 0.125f);
  if (hv < 16) scale *= 0.125f;
  s16x8 o;
#pragma unroll
  for (int j = 0; j < 8; ++j) o[j] = (short)f2bf(f[j] * scale);
  *(s16x8*)p = o;
}

// ---------------------------------------------------------------------------
// 5) V transpose: qkv v-part -> Vt[bh][d][t]
// ---------------------------------------------------------------------------
__global__ __launch_bounds__(256) void k_vtrans(const unsigned short* __restrict__ qkv,
                                                unsigned short* __restrict__ Vt) {
  const int tt = blockIdx.x & 31, bh = blockIdx.x >> 5;
  const int b = bh >> 4, h = bh & 15;
  const int t0 = tt * 64;
  __shared__ unsigned short tile[64][80];
  const int tid = threadIdx.x;
#pragma unroll
  for (int half = 0; half < 2; ++half) {
    const int tl = half * 32 + (tid >> 3), part = tid & 7;
    s16x8 v = *(const s16x8*)(qkv + (size_t)(b * SEQ + t0 + tl) * QKVC + 2 * DMODEL +
                              h * HDIM + part * 8);
    *(s16x8*)(&tile[tl][part * 8]) = v;
  }
  __syncthreads();
#pragma unroll
  for (int half = 0; half < 2; ++half) {
    const int d = half * 32 + (tid >> 3), tp = tid & 7;
    s16x8 o;
#pragma unroll
    for (int j = 0; j < 8; ++j) o[j] = (short)tile[tp * 8 + j][d];
    *(s16x8*)(Vt + (size_t)(bh * HDIM + d) * SEQ + t0 + tp * 8) = o;
  }
}

// ---------------------------------------------------------------------------
// 6) flash attention, 32x32 MFMA + in-register repack. R8 bisect: the
//    cross-half softmax reduces now use KNOWN-GOOD __shfl_xor(x,32)
//    (R1-R5-verified) instead of hand-rolled permlane self-swap helpers,
//    and defer-max is removed (classic always-rescale online softmax).
//    Repack (verified == m214 recipe), stagger, epilogue unchanged.
// ---------------------------------------------------------------------------
__global__ __launch_bounds__(256) void k_attn(const unsigned short* __restrict__ qkv,
                                              const unsigned short* __restrict__ Vt,
                                              unsigned short* __restrict__ O) {
  const int wave = threadIdx.x >> 6, lane = threadIdx.x & 63;
  const int l31 = lane & 31, hi = lane >> 5;
  const int bh = blockIdx.x >> 4;          // 16 blocks per (b,h)
  const int qg = blockIdx.x & 15;
  const int b = bh >> 4, h = bh & 15;
  const int wv = qg * 4 + wave;            // 0..63 within this head
  const int q0 = wv * 32;
  const int stag = wv;                     // unique start tile per wave

  // Q B-fragments (col=q=l31, k=8*hi+j), 1/8 scale pre-folded. 4 k-steps.
  const unsigned short* qp =
      qkv + (size_t)(b * SEQ + q0 + l31) * QKVC + h * HDIM + hi * 8;
  const s16x8 qf0 = *(const s16x8*)(qp);
  const s16x8 qf1 = *(const s16x8*)(qp + 16);
  const s16x8 qf2 = *(const s16x8*)(qp + 32);
  const s16x8 qf3 = *(const s16x8*)(qp + 48);

  const unsigned short* kbase =
      qkv + (size_t)(b * SEQ + l31) * QKVC + DMODEL + h * HDIM + hi * 8;
  const unsigned short* vbase = Vt + (size_t)(bh * HDIM + l31) * SEQ + hi * 8;

  f32x16 acc0 = {0,0,0,0,0,0,0,0,0,0,0,0,0,0,0,0};
  f32x16 acc1 = {0,0,0,0,0,0,0,0,0,0,0,0,0,0,0,0};
  float m = -1e30f, l = 0.f;

#pragma unroll 2
  for (int i = 0; i < 64; ++i) {
    const int kt = ((i + stag) & 63) << 5;
    // ---- K A-fragments: row=key=l31, k=8*hi+j, 4 k-steps of 16 ----
    const unsigned short* kp = kbase + (size_t)kt * QKVC;
    const s16x8 k0 = *(const s16x8*)(kp);
    const s16x8 k1 = *(const s16x8*)(kp + 16);
    const s16x8 k2 = *(const s16x8*)(kp + 32);
    const s16x8 k3 = *(const s16x8*)(kp + 48);
    // ---- V^T A-fragments: row=d=l31 (+32 for acc1), k=key ----
    const unsigned short* vp = vbase + kt;
    const s16x8 v00 = *(const s16x8*)(vp);
    const s16x8 v01 = *(const s16x8*)(vp + 16);
    const s16x8 v10 = *(const s16x8*)(vp + (size_t)32 * SEQ);
    const s16x8 v11 = *(const s16x8*)(vp + (size_t)32 * SEQ + 16);

    // ---- S^T[32 keys][32 queries] ----
    f32x16 st = {0,0,0,0,0,0,0,0,0,0,0,0,0,0,0,0};
    __builtin_amdgcn_s_setprio(1);
    st = __builtin_amdgcn_mfma_f32_32x32x16_bf16(k0, qf0, st, 0, 0, 0);
    st = __builtin_amdgcn_mfma_f32_32x32x16_bf16(k1, qf1, st, 0, 0, 0);
    st = __builtin_amdgcn_mfma_f32_32x32x16_bf16(k2, qf2, st, 0, 0, 0);
    st = __builtin_amdgcn_mfma_f32_32x32x16_bf16(k3, qf3, st, 0, 0, 0);
    __builtin_amdgcn_s_setprio(0);

    // ---- in-lane max over 16, cross-half via KNOWN-GOOD shfl_xor ----
    float a0 = fmaxf(st[0], st[1]),   a1 = fmaxf(st[2], st[3]);
    float a2 = fmaxf(st[4], st[5]),   a3 = fmaxf(st[6], st[7]);
    float a4 = fmaxf(st[8], st[9]),   a5 = fmaxf(st[10], st[11]);
    float a6 = fmaxf(st[12], st[13]), a7 = fmaxf(st[14], st[15]);
    a0 = fmaxf(a0, a1); a2 = fmaxf(a2, a3); a4 = fmaxf(a4, a5); a6 = fmaxf(a6, a7);
    float t = fmaxf(fmaxf(a0, a2), fmaxf(a4, a6));
    const float tm = fmaxf(t, __shfl_xor(t, 32));

    // ---- classic online rescale (no defer) ----
    const float mnew = fmaxf(m, tm);
    const float c = __expf(m - mnew);
    m = mnew;
    l *= c;
#pragma unroll
    for (int r = 0; r < 16; ++r) { acc0[r] *= c; acc1[r] *= c; }

    // ---- P = exp(S - m), all in-lane ----
#pragma unroll
    for (int r = 0; r < 16; ++r) st[r] = __expf(st[r] - m);

    // ---- repack P -> B-fragments (== m214 recipe) ----
    unsigned P0 = pkbf(st[0], st[1]),   P1 = pkbf(st[2], st[3]);
    unsigned P2 = pkbf(st[4], st[5]),   P3 = pkbf(st[6], st[7]);
    unsigned P4 = pkbf(st[8], st[9]),   P5 = pkbf(st[10], st[11]);
    unsigned P6 = pkbf(st[12], st[13]), P7 = pkbf(st[14], st[15]);
    swp(P0, P2);   // P0 -> frag0.w0, P2 -> frag0.w2
    swp(P1, P3);   // P1 -> frag0.w1, P3 -> frag0.w3
    swp(P4, P6);   // P4 -> frag1.w0, P6 -> frag1.w2
    swp(P5, P7);   // P5 -> frag1.w1, P7 -> frag1.w3
    u32x4 w0; w0[0] = P0; w0[1] = P1; w0[2] = P2; w0[3] = P3;
    u32x4 w1; w1[0] = P4; w1[1] = P5; w1[2] = P6; w1[3] = P7;
    const s16x8 pf0 = __builtin_bit_cast(s16x8, w0);
    const s16x8 pf1 = __builtin_bit_cast(s16x8, w1);

    // ---- O^T += V^T * P^T ----
    __builtin_amdgcn_s_setprio(1);
    acc0 = __builtin_amdgcn_mfma_f32_32x32x16_bf16(v00, pf0, acc0, 0, 0, 0);
    acc0 = __builtin_amdgcn_mfma_f32_32x32x16_bf16(v01, pf1, acc0, 0, 0, 0);
    acc1 = __builtin_amdgcn_mfma_f32_32x32x16_bf16(v10, pf0, acc1, 0, 0, 0);
    acc1 = __builtin_amdgcn_mfma_f32_32x32x16_bf16(v11, pf1, acc1, 0, 0, 0);
    __builtin_amdgcn_s_setprio(0);

    // ---- row-sum (off the critical path), cross-half via shfl_xor ----
    float s0 = (st[0] + st[1]) + (st[2] + st[3]);
    float s1 = (st[4] + st[5]) + (st[6] + st[7]);
    float s2 = (st[8] + st[9]) + (st[10] + st[11]);
    float s3 = (st[12] + st[13]) + (st[14] + st[15]);
    float rsum = (s0 + s1) + (s2 + s3);
    l += rsum + __shfl_xor(rsum, 32);
  }

  // ---- epilogue: acc reg r -> d = nb*32 + 8*(r>>2) + 4*hi + (r&3), q = l31 ----
  const float inv = 1.f / l;
  unsigned short* ob = O + (size_t)(b * SEQ + q0 + l31) * DMODEL + h * HDIM;
#pragma unroll
  for (int g = 0; g < 4; ++g) {
    s16x4 o0 = { (short)f2bf(acc0[4 * g] * inv),     (short)f2bf(acc0[4 * g + 1] * inv),
                 (short)f2bf(acc0[4 * g + 2] * inv), (short)f2bf(acc0[4 * g + 3] * inv) };
    s16x4 o1 = { (short)f2bf(acc1[4 * g] * inv),     (short)f2bf(acc1[4 * g + 1] * inv),
                 (short)f2bf(acc1[4 * g + 2] * inv), (short)f2bf(acc1[4 * g + 3] * inv) };
    *(s16x4*)(ob + g * 8 + hi * 4) = o0;
    *(s16x4*)(ob + 32 + g * 8 + hi * 4) = o1;
  }
}

// ---------------------------------------------------------------------------
// launch: ws layout (bytes): Wq[0,6M) Wo[6M,8M) Xb[8M,16M) QKV[16M,40M) Vt[40M,48M)
// ---------------------------------------------------------------------------
extern "C" void kernel_launch(void* const* d_in, const int* in_sizes, int n_in,
                              void* d_out, int out_size, void* d_ws, size_t ws_size,
                              hipStream_t stream) {
  const float* x    = (const float*)d_in[0];
  const float* wqkv = (const float*)d_in[1];
  const float* wout = (const float*)d_in[2];
  char* ws = (char*)d_ws;
  unsigned short* Wq  = (unsigned short*)(ws);
  unsigned short* Wo  = (unsigned short*)(ws + 6291456);
  unsigned short* Xb  = (unsigned short*)(ws + 8388608);
  unsigned short* QKV = (unsigned short*)(ws + 16777216);
  unsigned short* Vt  = (unsigned short*)(ws + 41943040);
  (void)in_sizes; (void)n_in; (void)out_size; (void)ws_size;

  k_wnorm<<<QKVC, 256, 0, stream>>>(wqkv, Wq);
  k_wnorm<<<DMODEL, 256, 0, stream>>>(wout, Wo);
  k_cast<<<(NROWS * DMODEL) / 1024, 256, 0, stream>>>(x, Xb);
  k_gemm_bt<1><<<(NROWS / 128) * (QKVC / 128), 256, 0, stream>>>(
      Xb, Wq, (void*)QKV, NROWS, QKVC, DMODEL);
  k_qknorm<<<NROWS, 256, 0, stream>>>(QKV);
  k_vtrans<<<BATCH * NHEAD * (SEQ / 64), 256, 0, stream>>>(QKV, Vt);
  k_attn<<<BATCH * NHEAD * 16, 256, 0, stream>>>(QKV, Vt, Xb);
  k_gemm_bt<0><<<(NROWS / 128) * (DMODEL / 128), 256, 0, stream>>>(
      Xb, Wo, d_out, NROWS, DMODEL, DMODEL);
}

// Round 9
// 210.743 us; speedup vs baseline: 1.9234x; 1.0071x over previous
//
#include <hip/hip_runtime.h>

// ---------------- fixed problem shape ----------------
#define BATCH  2
#define SEQ    2048
#define DMODEL 1024
#define NHEAD  16
#define HDIM   64
#define NROWS  (BATCH * SEQ)   // 4096
#define QKVC   (3 * DMODEL)    // 3072

typedef float f32x4 __attribute__((ext_vector_type(4)));
typedef float f32x16 __attribute__((ext_vector_type(16)));
typedef short s16x8 __attribute__((ext_vector_type(8)));
typedef short s16x4 __attribute__((ext_vector_type(4)));
typedef unsigned int u32x4 __attribute__((ext_vector_type(4)));

__device__ __forceinline__ unsigned short f2bf(float f) {
  unsigned int u = __float_as_uint(f);
  u = (u + 0x7FFFu + ((u >> 16) & 1u)) >> 16;   // RNE
  return (unsigned short)u;
}
__device__ __forceinline__ float bf2f(unsigned short s) {
  return __uint_as_float(((unsigned int)s) << 16);
}
// pack two f32 -> two bf16 in one u32 (low = a, high = b)
__device__ __forceinline__ unsigned pkbf(float a, float b) {
  unsigned r;
  asm("v_cvt_pk_bf16_f32 %0, %1, %2" : "=v"(r) : "v"(a), "v"(b));
  return r;
}
// v_permlane32_swap_b32 DST, SRC: DST[32:63] <-> SRC[0:31]
// SAFE only with two genuinely distinct values (compiler may coalesce
// equal-valued copies into one register -> self-swap garbage; R7 bug).
__device__ __forceinline__ void swp(unsigned &a, unsigned &b) {
  asm volatile("v_permlane32_swap_b32 %0, %1" : "+v"(a), "+v"(b));
}

// ---------------------------------------------------------------------------
// 1) row-normalize f32 weight rows (len 1024) -> bf16
// ---------------------------------------------------------------------------
__global__ __launch_bounds__(256) void k_wnorm(const float* __restrict__ W,
                                               unsigned short* __restrict__ Wh) {
  const int row = blockIdx.x, tid = threadIdx.x;
  const float4* rp = (const float4*)(W + (size_t)row * DMODEL);
  float4 v = rp[tid];
  float ss = v.x * v.x + v.y * v.y + v.z * v.z + v.w * v.w;
#pragma unroll
  for (int m = 1; m < 64; m <<= 1) ss += __shfl_xor(ss, m);
  __shared__ float part[4];
  if ((tid & 63) == 0) part[tid >> 6] = ss;
  __syncthreads();
  const float tot = part[0] + part[1] + part[2] + part[3];
  const float scale = 0.03125f / (1e-4f + sqrtf(tot) * 0.03125f);
  unsigned short* op = Wh + (size_t)row * DMODEL + tid * 4;
  op[0] = f2bf(v.x * scale); op[1] = f2bf(v.y * scale);
  op[2] = f2bf(v.z * scale); op[3] = f2bf(v.w * scale);
}

// ---------------------------------------------------------------------------
// 2) f32 -> bf16 cast
// ---------------------------------------------------------------------------
__global__ __launch_bounds__(256) void k_cast(const float* __restrict__ X,
                                              unsigned short* __restrict__ Xb) {
  const int i = blockIdx.x * 256 + threadIdx.x;
  const float4 v = ((const float4*)X)[i];
  ushort4 o = { f2bf(v.x), f2bf(v.y), f2bf(v.z), f2bf(v.w) };
  ((ushort4*)Xb)[i] = o;
}

// ---------------------------------------------------------------------------
// 3) C[M][N] = A[M][K] * B[N][K]^T  (unchanged)
// ---------------------------------------------------------------------------
#define LDP 88
template <int WRITE_BF16>
__global__ __launch_bounds__(256) void k_gemm_bt(const unsigned short* __restrict__ A,
                                                 const unsigned short* __restrict__ Bm,
                                                 void* __restrict__ Cv,
                                                 int M, int N, int K) {
  __shared__ unsigned short As[128 * LDP];
  __shared__ unsigned short Bs[128 * LDP];
  const int tid = threadIdx.x;
  const int nbn = N >> 7;
  const int bm = (blockIdx.x / nbn) << 7;
  const int bn = (blockIdx.x % nbn) << 7;
  const int wave = tid >> 6, lane = tid & 63;
  const int wr = (wave >> 1) << 6, wc = (wave & 1) << 6;
  const int l16 = lane & 15, lg = lane >> 4;

  f32x4 acc[4][4];
#pragma unroll
  for (int m = 0; m < 4; ++m)
#pragma unroll
    for (int n = 0; n < 4; ++n) acc[m][n] = (f32x4){0.f, 0.f, 0.f, 0.f};

  for (int k0 = 0; k0 < K; k0 += 64) {
    s16x8 ra[4], rb[4];
#pragma unroll
    for (int it = 0; it < 4; ++it) {
      const int c = it * 256 + tid;
      const int r = c >> 3, col = (c & 7) << 3;
      ra[it] = *(const s16x8*)(A + (size_t)(bm + r) * K + k0 + col);
      rb[it] = *(const s16x8*)(Bm + (size_t)(bn + r) * K + k0 + col);
    }
    __syncthreads();
#pragma unroll
    for (int it = 0; it < 4; ++it) {
      const int c = it * 256 + tid;
      const int r = c >> 3, col = (c & 7) << 3;
      *(s16x8*)(As + r * LDP + col) = ra[it];
      *(s16x8*)(Bs + r * LDP + col) = rb[it];
    }
    __syncthreads();
#pragma unroll
    for (int ks = 0; ks < 2; ++ks) {
      s16x8 af[4], bq[4];
#pragma unroll
      for (int m = 0; m < 4; ++m)
        af[m] = *(const s16x8*)(As + (wr + m * 16 + l16) * LDP + ks * 32 + lg * 8);
#pragma unroll
      for (int n = 0; n < 4; ++n)
        bq[n] = *(const s16x8*)(Bs + (wc + n * 16 + l16) * LDP + ks * 32 + lg * 8);
#pragma unroll
      for (int m = 0; m < 4; ++m)
#pragma unroll
        for (int n = 0; n < 4; ++n)
          acc[m][n] = __builtin_amdgcn_mfma_f32_16x16x32_bf16(af[m], bq[n], acc[m][n], 0, 0, 0);
    }
  }
  if (WRITE_BF16) {
    unsigned short* C = (unsigned short*)Cv;
#pragma unroll
    for (int m = 0; m < 4; ++m)
#pragma unroll
      for (int n = 0; n < 4; ++n)
#pragma unroll
        for (int r = 0; r < 4; ++r)
          C[(size_t)(bm + wr + m * 16 + lg * 4 + r) * N + (bn + wc + n * 16 + l16)] =
              f2bf(acc[m][n][r]);
  } else {
    float* C = (float*)Cv;
#pragma unroll
    for (int m = 0; m < 4; ++m)
#pragma unroll
      for (int n = 0; n < 4; ++n)
#pragma unroll
        for (int r = 0; r < 4; ++r)
          C[(size_t)(bm + wr + m * 16 + lg * 4 + r) * N + (bn + wc + n * 16 + l16)] =
              acc[m][n][r];
  }
}

// ---------------------------------------------------------------------------
// 4) normalize q,k head-vectors in-place; q rows fold attn scale 1/8
// ---------------------------------------------------------------------------
__global__ __launch_bounds__(256) void k_qknorm(unsigned short* __restrict__ qkv) {
  const int row = blockIdx.x, tid = threadIdx.x;
  const int hv = tid >> 3, g = tid & 7;
  const int base = (hv < 16) ? (hv * HDIM) : (DMODEL + (hv - 16) * HDIM);
  unsigned short* p = qkv + (size_t)row * QKVC + base + g * 8;
  s16x8 v = *(const s16x8*)p;
  float f[8];
  float ss = 0.f;
#pragma unroll
  for (int j = 0; j < 8; ++j) { f[j] = bf2f((unsigned short)v[j]); ss += f[j] * f[j]; }
  ss += __shfl_xor(ss, 1); ss += __shfl_xor(ss, 2); ss += __shfl_xor(ss, 4);
  float scale = 1.f / (1e-4f + sqrtf(ss) * 0.125f);
  if (hv < 16) scale *= 0.125f;
  s16x8 o;
#pragma unroll
  for (int j = 0; j < 8; ++j) o[j] = (short)f2bf(f[j] * scale);
  *(s16x8*)p = o;
}

// ---------------------------------------------------------------------------
// 5) V transpose: qkv v-part -> Vt[bh][d][t]
// ---------------------------------------------------------------------------
__global__ __launch_bounds__(256) void k_vtrans(const unsigned short* __restrict__ qkv,
                                                unsigned short* __restrict__ Vt) {
  const int tt = blockIdx.x & 31, bh = blockIdx.x >> 5;
  const int b = bh >> 4, h = bh & 15;
  const int t0 = tt * 64;
  __shared__ unsigned short tile[64][80];
  const int tid = threadIdx.x;
#pragma unroll
  for (int half = 0; half < 2; ++half) {
    const int tl = half * 32 + (tid >> 3), part = tid & 7;
    s16x8 v = *(const s16x8*)(qkv + (size_t)(b * SEQ + t0 + tl) * QKVC + 2 * DMODEL +
                              h * HDIM + part * 8);
    *(s16x8*)(&tile[tl][part * 8]) = v;
  }
  __syncthreads();
#pragma unroll
  for (int half = 0; half < 2; ++half) {
    const int d = half * 32 + (tid >> 3), tp = tid & 7;
    s16x8 o;
#pragma unroll
    for (int j = 0; j < 8; ++j) o[j] = (short)tile[tp * 8 + j][d];
    *(s16x8*)(Vt + (size_t)(bh * HDIM + d) * SEQ + t0 + tp * 8) = o;
  }
}

// ---------------------------------------------------------------------------
// 6) flash attention (R8-verified math) + R9 structure:
//    - XCD-clustered logical blocks: each XCD owns 4 complete heads ->
//      2 MB K/V working set per 4 MB L2 (was 16 MB, 4.5x overfetch).
//    - Key-split x2 (R5-proven LDS merge): 8 waves/block; waves (qw, qw+4)
//      cover disjoint 1024-key halves -> 4 waves/SIMD for latency hiding.
//    - No stagger: synced waves share L2-resident lines.
// ---------------------------------------------------------------------------
__global__ __launch_bounds__(512) void k_attn(const unsigned short* __restrict__ qkv,
                                              const unsigned short* __restrict__ Vt,
                                              unsigned short* __restrict__ O) {
  const int bid = blockIdx.x;
  const int logical = ((bid & 7) << 6) + (bid >> 3);   // XCD clustering (512%8==0)
  const int bh = logical >> 4, qt = logical & 15;
  const int b = bh >> 4, h = bh & 15;
  const int wave = threadIdx.x >> 6, lane = threadIdx.x & 63;
  const int l31 = lane & 31, hi = lane >> 5;
  const int qw = wave & 3, half = wave >> 2;
  const int q0 = qt * 128 + qw * 32;

  __shared__ float OO[4][64][33];    // padded: conflict-free merge
  __shared__ float MM[4][64], LL[4][64];

  // Q B-fragments (col=q=l31, k=8*hi+j), 1/8 scale pre-folded. 4 k-steps.
  const unsigned short* qp =
      qkv + (size_t)(b * SEQ + q0 + l31) * QKVC + h * HDIM + hi * 8;
  const s16x8 qf0 = *(const s16x8*)(qp);
  const s16x8 qf1 = *(const s16x8*)(qp + 16);
  const s16x8 qf2 = *(const s16x8*)(qp + 32);
  const s16x8 qf3 = *(const s16x8*)(qp + 48);

  const unsigned short* kbase =
      qkv + (size_t)(b * SEQ + l31) * QKVC + DMODEL + h * HDIM + hi * 8;
  const unsigned short* vbase = Vt + (size_t)(bh * HDIM + l31) * SEQ + hi * 8;

  f32x16 acc0 = {0,0,0,0,0,0,0,0,0,0,0,0,0,0,0,0};
  f32x16 acc1 = {0,0,0,0,0,0,0,0,0,0,0,0,0,0,0,0};
  float m = -1e30f, l = 0.f;

#pragma unroll 2
  for (int i = 0; i < 32; ++i) {
    const int kt = (half << 10) + (i << 5);
    // ---- K A-fragments: row=key=l31, k=8*hi+j, 4 k-steps of 16 ----
    const unsigned short* kp = kbase + (size_t)kt * QKVC;
    const s16x8 k0 = *(const s16x8*)(kp);
    const s16x8 k1 = *(const s16x8*)(kp + 16);
    const s16x8 k2 = *(const s16x8*)(kp + 32);
    const s16x8 k3 = *(const s16x8*)(kp + 48);
    // ---- V^T A-fragments: row=d=l31 (+32 for acc1), k=key ----
    const unsigned short* vp = vbase + kt;
    const s16x8 v00 = *(const s16x8*)(vp);
    const s16x8 v01 = *(const s16x8*)(vp + 16);
    const s16x8 v10 = *(const s16x8*)(vp + (size_t)32 * SEQ);
    const s16x8 v11 = *(const s16x8*)(vp + (size_t)32 * SEQ + 16);

    // ---- S^T[32 keys][32 queries] ----
    f32x16 st = {0,0,0,0,0,0,0,0,0,0,0,0,0,0,0,0};
    __builtin_amdgcn_s_setprio(1);
    st = __builtin_amdgcn_mfma_f32_32x32x16_bf16(k0, qf0, st, 0, 0, 0);
    st = __builtin_amdgcn_mfma_f32_32x32x16_bf16(k1, qf1, st, 0, 0, 0);
    st = __builtin_amdgcn_mfma_f32_32x32x16_bf16(k2, qf2, st, 0, 0, 0);
    st = __builtin_amdgcn_mfma_f32_32x32x16_bf16(k3, qf3, st, 0, 0, 0);
    __builtin_amdgcn_s_setprio(0);

    // ---- in-lane max over 16, cross-half via shfl_xor(32) ----
    float a0 = fmaxf(st[0], st[1]),   a1 = fmaxf(st[2], st[3]);
    float a2 = fmaxf(st[4], st[5]),   a3 = fmaxf(st[6], st[7]);
    float a4 = fmaxf(st[8], st[9]),   a5 = fmaxf(st[10], st[11]);
    float a6 = fmaxf(st[12], st[13]), a7 = fmaxf(st[14], st[15]);
    a0 = fmaxf(a0, a1); a2 = fmaxf(a2, a3); a4 = fmaxf(a4, a5); a6 = fmaxf(a6, a7);
    float t = fmaxf(fmaxf(a0, a2), fmaxf(a4, a6));
    const float tm = fmaxf(t, __shfl_xor(t, 32));

    // ---- classic online rescale ----
    const float mnew = fmaxf(m, tm);
    const float c = __expf(m - mnew);
    m = mnew;
    l *= c;
#pragma unroll
    for (int r = 0; r < 16; ++r) { acc0[r] *= c; acc1[r] *= c; }

    // ---- P = exp(S - m), all in-lane ----
#pragma unroll
    for (int r = 0; r < 16; ++r) st[r] = __expf(st[r] - m);

    // ---- repack P -> B-fragments (verified m214 recipe) ----
    unsigned P0 = pkbf(st[0], st[1]),   P1 = pkbf(st[2], st[3]);
    unsigned P2 = pkbf(st[4], st[5]),   P3 = pkbf(st[6], st[7]);
    unsigned P4 = pkbf(st[8], st[9]),   P5 = pkbf(st[10], st[11]);
    unsigned P6 = pkbf(st[12], st[13]), P7 = pkbf(st[14], st[15]);
    swp(P0, P2);
    swp(P1, P3);
    swp(P4, P6);
    swp(P5, P7);
    u32x4 w0; w0[0] = P0; w0[1] = P1; w0[2] = P2; w0[3] = P3;
    u32x4 w1; w1[0] = P4; w1[1] = P5; w1[2] = P6; w1[3] = P7;
    const s16x8 pf0 = __builtin_bit_cast(s16x8, w0);
    const s16x8 pf1 = __builtin_bit_cast(s16x8, w1);

    // ---- O^T += V^T * P^T ----
    __builtin_amdgcn_s_setprio(1);
    acc0 = __builtin_amdgcn_mfma_f32_32x32x16_bf16(v00, pf0, acc0, 0, 0, 0);
    acc0 = __builtin_amdgcn_mfma_f32_32x32x16_bf16(v01, pf1, acc0, 0, 0, 0);
    acc1 = __builtin_amdgcn_mfma_f32_32x32x16_bf16(v10, pf0, acc1, 0, 0, 0);
    acc1 = __builtin_amdgcn_mfma_f32_32x32x16_bf16(v11, pf1, acc1, 0, 0, 0);
    __builtin_amdgcn_s_setprio(0);

    // ---- row-sum, cross-half via shfl_xor ----
    float s0 = (st[0] + st[1]) + (st[2] + st[3]);
    float s1 = (st[4] + st[5]) + (st[6] + st[7]);
    float s2 = (st[8] + st[9]) + (st[10] + st[11]);
    float s3 = (st[12] + st[13]) + (st[14] + st[15]);
    float rsum = (s0 + s1) + (s2 + s3);
    l += rsum + __shfl_xor(rsum, 32);
  }

  // ---- cross-half merge (R5-proven pattern) ----
  if (half) {
#pragma unroll
    for (int r = 0; r < 16; ++r) {
      OO[qw][lane][r] = acc0[r];
      OO[qw][lane][16 + r] = acc1[r];
    }
    MM[qw][lane] = m;
    LL[qw][lane] = l;
  }
  __syncthreads();
  if (!half) {
    const float m2 = MM[qw][lane], l2 = LL[qw][lane];
    const float M = fmaxf(m, m2);
    const float c1 = __expf(m - M), c2 = __expf(m2 - M);
    const float inv = 1.f / (l * c1 + l2 * c2);
    // epilogue: acc reg r -> d = nb*32 + 8*(r>>2) + 4*hi + (r&3), q = l31
    unsigned short* ob = O + (size_t)(b * SEQ + q0 + l31) * DMODEL + h * HDIM;
#pragma unroll
    for (int g = 0; g < 4; ++g) {
      float e00 = (acc0[4 * g]     * c1 + OO[qw][lane][4 * g]      * c2) * inv;
      float e01 = (acc0[4 * g + 1] * c1 + OO[qw][lane][4 * g + 1]  * c2) * inv;
      float e02 = (acc0[4 * g + 2] * c1 + OO[qw][lane][4 * g + 2]  * c2) * inv;
      float e03 = (acc0[4 * g + 3] * c1 + OO[qw][lane][4 * g + 3]  * c2) * inv;
      float e10 = (acc1[4 * g]     * c1 + OO[qw][lane][16 + 4 * g]     * c2) * inv;
      float e11 = (acc1[4 * g + 1] * c1 + OO[qw][lane][16 + 4 * g + 1] * c2) * inv;
      float e12 = (acc1[4 * g + 2] * c1 + OO[qw][lane][16 + 4 * g + 2] * c2) * inv;
      float e13 = (acc1[4 * g + 3] * c1 + OO[qw][lane][16 + 4 * g + 3] * c2) * inv;
      s16x4 o0 = { (short)f2bf(e00), (short)f2bf(e01), (short)f2bf(e02), (short)f2bf(e03) };
      s16x4 o1 = { (short)f2bf(e10), (short)f2bf(e11), (short)f2bf(e12), (short)f2bf(e13) };
      *(s16x4*)(ob + g * 8 + hi * 4) = o0;
      *(s16x4*)(ob + 32 + g * 8 + hi * 4) = o1;
    }
  }
}

// ---------------------------------------------------------------------------
// launch: ws layout (bytes): Wq[0,6M) Wo[6M,8M) Xb[8M,16M) QKV[16M,40M) Vt[40M,48M)
// ---------------------------------------------------------------------------
extern "C" void kernel_launch(void* const* d_in, const int* in_sizes, int n_in,
                              void* d_out, int out_size, void* d_ws, size_t ws_size,
                              hipStream_t stream) {
  const float* x    = (const float*)d_in[0];
  const float* wqkv = (const float*)d_in[1];
  const float* wout = (const float*)d_in[2];
  char* ws = (char*)d_ws;
  unsigned short* Wq  = (unsigned short*)(ws);
  unsigned short* Wo  = (unsigned short*)(ws + 6291456);
  unsigned short* Xb  = (unsigned short*)(ws + 8388608);
  unsigned short* QKV = (unsigned short*)(ws + 16777216);
  unsigned short* Vt  = (unsigned short*)(ws + 41943040);
  (void)in_sizes; (void)n_in; (void)out_size; (void)ws_size;

  k_wnorm<<<QKVC, 256, 0, stream>>>(wqkv, Wq);
  k_wnorm<<<DMODEL, 256, 0, stream>>>(wout, Wo);
  k_cast<<<(NROWS * DMODEL) / 1024, 256, 0, stream>>>(x, Xb);
  k_gemm_bt<1><<<(NROWS / 128) * (QKVC / 128), 256, 0, stream>>>(
      Xb, Wq, (void*)QKV, NROWS, QKVC, DMODEL);
  k_qknorm<<<NROWS, 256, 0, stream>>>(QKV);
  k_vtrans<<<BATCH * NHEAD * (SEQ / 64), 256, 0, stream>>>(QKV, Vt);
  k_attn<<<BATCH * NHEAD * 16, 512, 0, stream>>>(QKV, Vt, Xb);
  k_gemm_bt<0><<<(NROWS / 128) * (DMODEL / 128), 256, 0, stream>>>(
      Xb, Wo, d_out, NROWS, DMODEL, DMODEL);
}

// Round 10
// 209.851 us; speedup vs baseline: 1.9316x; 1.0043x over previous
//
#include <hip/hip_runtime.h>

// ---------------- fixed problem shape ----------------
#define BATCH  2
#define SEQ    2048
#define DMODEL 1024
#define NHEAD  16
#define HDIM   64
#define NROWS  (BATCH * SEQ)   // 4096
#define QKVC   (3 * DMODEL)    // 3072

typedef float f32x4 __attribute__((ext_vector_type(4)));
typedef float f32x16 __attribute__((ext_vector_type(16)));
typedef short s16x8 __attribute__((ext_vector_type(8)));
typedef short s16x4 __attribute__((ext_vector_type(4)));
typedef unsigned int u32x4 __attribute__((ext_vector_type(4)));

__device__ __forceinline__ unsigned short f2bf(float f) {
  unsigned int u = __float_as_uint(f);
  u = (u + 0x7FFFu + ((u >> 16) & 1u)) >> 16;   // RNE
  return (unsigned short)u;
}
__device__ __forceinline__ float bf2f(unsigned short s) {
  return __uint_as_float(((unsigned int)s) << 16);
}
// pack two f32 -> two bf16 in one u32 (low = a, high = b)
__device__ __forceinline__ unsigned pkbf(float a, float b) {
  unsigned r;
  asm("v_cvt_pk_bf16_f32 %0, %1, %2" : "=v"(r) : "v"(a), "v"(b));
  return r;
}
// v_permlane32_swap_b32 DST, SRC: DST[32:63] <-> SRC[0:31]
// SAFE only with two genuinely distinct values (R7 lesson: equal-valued
// copies may be coalesced into one register -> self-swap garbage).
__device__ __forceinline__ void swp(unsigned &a, unsigned &b) {
  asm volatile("v_permlane32_swap_b32 %0, %1" : "+v"(a), "+v"(b));
}

// ---------------------------------------------------------------------------
// 1) row-normalize f32 weight rows (len 1024) -> bf16
// ---------------------------------------------------------------------------
__global__ __launch_bounds__(256) void k_wnorm(const float* __restrict__ W,
                                               unsigned short* __restrict__ Wh) {
  const int row = blockIdx.x, tid = threadIdx.x;
  const float4* rp = (const float4*)(W + (size_t)row * DMODEL);
  float4 v = rp[tid];
  float ss = v.x * v.x + v.y * v.y + v.z * v.z + v.w * v.w;
#pragma unroll
  for (int m = 1; m < 64; m <<= 1) ss += __shfl_xor(ss, m);
  __shared__ float part[4];
  if ((tid & 63) == 0) part[tid >> 6] = ss;
  __syncthreads();
  const float tot = part[0] + part[1] + part[2] + part[3];
  const float scale = 0.03125f / (1e-4f + sqrtf(tot) * 0.03125f);
  unsigned short* op = Wh + (size_t)row * DMODEL + tid * 4;
  op[0] = f2bf(v.x * scale); op[1] = f2bf(v.y * scale);
  op[2] = f2bf(v.z * scale); op[3] = f2bf(v.w * scale);
}

// ---------------------------------------------------------------------------
// 2) f32 -> bf16 cast
// ---------------------------------------------------------------------------
__global__ __launch_bounds__(256) void k_cast(const float* __restrict__ X,
                                              unsigned short* __restrict__ Xb) {
  const int i = blockIdx.x * 256 + threadIdx.x;
  const float4 v = ((const float4*)X)[i];
  ushort4 o = { f2bf(v.x), f2bf(v.y), f2bf(v.z), f2bf(v.w) };
  ((ushort4*)Xb)[i] = o;
}

// ---------------------------------------------------------------------------
// 3) C[M][N] = A[M][K] * B[N][K]^T  (unchanged)
// ---------------------------------------------------------------------------
#define LDP 88
template <int WRITE_BF16>
__global__ __launch_bounds__(256) void k_gemm_bt(const unsigned short* __restrict__ A,
                                                 const unsigned short* __restrict__ Bm,
                                                 void* __restrict__ Cv,
                                                 int M, int N, int K) {
  __shared__ unsigned short As[128 * LDP];
  __shared__ unsigned short Bs[128 * LDP];
  const int tid = threadIdx.x;
  const int nbn = N >> 7;
  const int bm = (blockIdx.x / nbn) << 7;
  const int bn = (blockIdx.x % nbn) << 7;
  const int wave = tid >> 6, lane = tid & 63;
  const int wr = (wave >> 1) << 6, wc = (wave & 1) << 6;
  const int l16 = lane & 15, lg = lane >> 4;

  f32x4 acc[4][4];
#pragma unroll
  for (int m = 0; m < 4; ++m)
#pragma unroll
    for (int n = 0; n < 4; ++n) acc[m][n] = (f32x4){0.f, 0.f, 0.f, 0.f};

  for (int k0 = 0; k0 < K; k0 += 64) {
    s16x8 ra[4], rb[4];
#pragma unroll
    for (int it = 0; it < 4; ++it) {
      const int c = it * 256 + tid;
      const int r = c >> 3, col = (c & 7) << 3;
      ra[it] = *(const s16x8*)(A + (size_t)(bm + r) * K + k0 + col);
      rb[it] = *(const s16x8*)(Bm + (size_t)(bn + r) * K + k0 + col);
    }
    __syncthreads();
#pragma unroll
    for (int it = 0; it < 4; ++it) {
      const int c = it * 256 + tid;
      const int r = c >> 3, col = (c & 7) << 3;
      *(s16x8*)(As + r * LDP + col) = ra[it];
      *(s16x8*)(Bs + r * LDP + col) = rb[it];
    }
    __syncthreads();
#pragma unroll
    for (int ks = 0; ks < 2; ++ks) {
      s16x8 af[4], bq[4];
#pragma unroll
      for (int m = 0; m < 4; ++m)
        af[m] = *(const s16x8*)(As + (wr + m * 16 + l16) * LDP + ks * 32 + lg * 8);
#pragma unroll
      for (int n = 0; n < 4; ++n)
        bq[n] = *(const s16x8*)(Bs + (wc + n * 16 + l16) * LDP + ks * 32 + lg * 8);
#pragma unroll
      for (int m = 0; m < 4; ++m)
#pragma unroll
        for (int n = 0; n < 4; ++n)
          acc[m][n] = __builtin_amdgcn_mfma_f32_16x16x32_bf16(af[m], bq[n], acc[m][n], 0, 0, 0);
    }
  }
  if (WRITE_BF16) {
    unsigned short* C = (unsigned short*)Cv;
#pragma unroll
    for (int m = 0; m < 4; ++m)
#pragma unroll
      for (int n = 0; n < 4; ++n)
#pragma unroll
        for (int r = 0; r < 4; ++r)
          C[(size_t)(bm + wr + m * 16 + lg * 4 + r) * N + (bn + wc + n * 16 + l16)] =
              f2bf(acc[m][n][r]);
  } else {
    float* C = (float*)Cv;
#pragma unroll
    for (int m = 0; m < 4; ++m)
#pragma unroll
      for (int n = 0; n < 4; ++n)
#pragma unroll
        for (int r = 0; r < 4; ++r)
          C[(size_t)(bm + wr + m * 16 + lg * 4 + r) * N + (bn + wc + n * 16 + l16)] =
              acc[m][n][r];
  }
}

// ---------------------------------------------------------------------------
// 4) normalize q,k head-vectors in-place; q rows fold attn scale 1/8
// ---------------------------------------------------------------------------
__global__ __launch_bounds__(256) void k_qknorm(unsigned short* __restrict__ qkv) {
  const int row = blockIdx.x, tid = threadIdx.x;
  const int hv = tid >> 3, g = tid & 7;
  const int base = (hv < 16) ? (hv * HDIM) : (DMODEL + (hv - 16) * HDIM);
  unsigned short* p = qkv + (size_t)row * QKVC + base + g * 8;
  s16x8 v = *(const s16x8*)p;
  float f[8];
  float ss = 0.f;
#pragma unroll
  for (int j = 0; j < 8; ++j) { f[j] = bf2f((unsigned short)v[j]); ss += f[j] * f[j]; }
  ss += __shfl_xor(ss, 1); ss += __shfl_xor(ss, 2); ss += __shfl_xor(ss, 4);
  float scale = 1.f / (1e-4f + sqrtf(ss) * 0.125f);
  if (hv < 16) scale *= 0.125f;
  s16x8 o;
#pragma unroll
  for (int j = 0; j < 8; ++j) o[j] = (short)f2bf(f[j] * scale);
  *(s16x8*)p = o;
}

// ---------------------------------------------------------------------------
// 5) V transpose: qkv v-part -> Vt[bh][d][t]
// ---------------------------------------------------------------------------
__global__ __launch_bounds__(256) void k_vtrans(const unsigned short* __restrict__ qkv,
                                                unsigned short* __restrict__ Vt) {
  const int tt = blockIdx.x & 31, bh = blockIdx.x >> 5;
  const int b = bh >> 4, h = bh & 15;
  const int t0 = tt * 64;
  __shared__ unsigned short tile[64][80];
  const int tid = threadIdx.x;
#pragma unroll
  for (int half = 0; half < 2; ++half) {
    const int tl = half * 32 + (tid >> 3), part = tid & 7;
    s16x8 v = *(const s16x8*)(qkv + (size_t)(b * SEQ + t0 + tl) * QKVC + 2 * DMODEL +
                              h * HDIM + part * 8);
    *(s16x8*)(&tile[tl][part * 8]) = v;
  }
  __syncthreads();
#pragma unroll
  for (int half = 0; half < 2; ++half) {
    const int d = half * 32 + (tid >> 3), tp = tid & 7;
    s16x8 o;
#pragma unroll
    for (int j = 0; j < 8; ++j) o[j] = (short)tile[tp * 8 + j][d];
    *(s16x8*)(Vt + (size_t)(bh * HDIM + d) * SEQ + t0 + tp * 8) = o;
  }
}

// ---------------------------------------------------------------------------
// 6) flash attention, R10: FIXED-MAX softmax. EDM2 normalization bounds
//    |s| <= 8 (||q_hat||=||k_hat||=8, scale 1/8) -> softmax with constant
//    M=8 is exact: P = exp(s-8) in [e^-16, 1]. Deletes the entire online-max
//    machinery from the chain (fmax tree, 120cy shuffle, acc rescale, l
//    shuffles) and the key-split merge becomes pure addition. setprio
//    removed (suspected wave serialization without phase role-split, m190).
// ---------------------------------------------------------------------------
__global__ __launch_bounds__(512) void k_attn(const unsigned short* __restrict__ qkv,
                                              const unsigned short* __restrict__ Vt,
                                              unsigned short* __restrict__ O) {
  const int bid = blockIdx.x;
  const int logical = ((bid & 7) << 6) + (bid >> 3);   // XCD clustering (512%8==0)
  const int bh = logical >> 4, qt = logical & 15;
  const int b = bh >> 4, h = bh & 15;
  const int wave = threadIdx.x >> 6, lane = threadIdx.x & 63;
  const int l31 = lane & 31, hi = lane >> 5;
  const int qw = wave & 3, half = wave >> 2;
  const int q0 = qt * 128 + qw * 32;

  __shared__ float OO[4][64][33];    // padded: conflict-free merge
  __shared__ float LL[4][64];

  // Q B-fragments (col=q=l31, k=8*hi+j), 1/8 scale pre-folded. 4 k-steps.
  const unsigned short* qp =
      qkv + (size_t)(b * SEQ + q0 + l31) * QKVC + h * HDIM + hi * 8;
  const s16x8 qf0 = *(const s16x8*)(qp);
  const s16x8 qf1 = *(const s16x8*)(qp + 16);
  const s16x8 qf2 = *(const s16x8*)(qp + 32);
  const s16x8 qf3 = *(const s16x8*)(qp + 48);

  const unsigned short* kbase =
      qkv + (size_t)(b * SEQ + l31) * QKVC + DMODEL + h * HDIM + hi * 8;
  const unsigned short* vbase = Vt + (size_t)(bh * HDIM + l31) * SEQ + hi * 8;

  f32x16 acc0 = {0,0,0,0,0,0,0,0,0,0,0,0,0,0,0,0};
  f32x16 acc1 = {0,0,0,0,0,0,0,0,0,0,0,0,0,0,0,0};
  float l = 0.f;

#pragma unroll 2
  for (int i = 0; i < 32; ++i) {
    const int kt = (half << 10) + (i << 5);
    // ---- K A-fragments: row=key=l31, k=8*hi+j, 4 k-steps of 16 ----
    const unsigned short* kp = kbase + (size_t)kt * QKVC;
    const s16x8 k0 = *(const s16x8*)(kp);
    const s16x8 k1 = *(const s16x8*)(kp + 16);
    const s16x8 k2 = *(const s16x8*)(kp + 32);
    const s16x8 k3 = *(const s16x8*)(kp + 48);
    // ---- V^T A-fragments: row=d=l31 (+32 for acc1), k=key ----
    const unsigned short* vp = vbase + kt;
    const s16x8 v00 = *(const s16x8*)(vp);
    const s16x8 v01 = *(const s16x8*)(vp + 16);
    const s16x8 v10 = *(const s16x8*)(vp + (size_t)32 * SEQ);
    const s16x8 v11 = *(const s16x8*)(vp + (size_t)32 * SEQ + 16);

    // ---- S^T[32 keys][32 queries] ----
    f32x16 st = {0,0,0,0,0,0,0,0,0,0,0,0,0,0,0,0};
    st = __builtin_amdgcn_mfma_f32_32x32x16_bf16(k0, qf0, st, 0, 0, 0);
    st = __builtin_amdgcn_mfma_f32_32x32x16_bf16(k1, qf1, st, 0, 0, 0);
    st = __builtin_amdgcn_mfma_f32_32x32x16_bf16(k2, qf2, st, 0, 0, 0);
    st = __builtin_amdgcn_mfma_f32_32x32x16_bf16(k3, qf3, st, 0, 0, 0);

    // ---- P = exp(S - 8), exact (|S| <= 8 by construction) ----
#pragma unroll
    for (int r = 0; r < 16; ++r) st[r] = __expf(st[r] - 8.f);

    // ---- in-lane denominator accumulation (off critical path) ----
    float s0 = (st[0] + st[1]) + (st[2] + st[3]);
    float s1 = (st[4] + st[5]) + (st[6] + st[7]);
    float s2 = (st[8] + st[9]) + (st[10] + st[11]);
    float s3 = (st[12] + st[13]) + (st[14] + st[15]);
    l += (s0 + s1) + (s2 + s3);

    // ---- repack P -> B-fragments (verified m214 recipe) ----
    unsigned P0 = pkbf(st[0], st[1]),   P1 = pkbf(st[2], st[3]);
    unsigned P2 = pkbf(st[4], st[5]),   P3 = pkbf(st[6], st[7]);
    unsigned P4 = pkbf(st[8], st[9]),   P5 = pkbf(st[10], st[11]);
    unsigned P6 = pkbf(st[12], st[13]), P7 = pkbf(st[14], st[15]);
    swp(P0, P2);
    swp(P1, P3);
    swp(P4, P6);
    swp(P5, P7);
    u32x4 w0; w0[0] = P0; w0[1] = P1; w0[2] = P2; w0[3] = P3;
    u32x4 w1; w1[0] = P4; w1[1] = P5; w1[2] = P6; w1[3] = P7;
    const s16x8 pf0 = __builtin_bit_cast(s16x8, w0);
    const s16x8 pf1 = __builtin_bit_cast(s16x8, w1);

    // ---- O^T += V^T * P^T ----
    acc0 = __builtin_amdgcn_mfma_f32_32x32x16_bf16(v00, pf0, acc0, 0, 0, 0);
    acc0 = __builtin_amdgcn_mfma_f32_32x32x16_bf16(v01, pf1, acc0, 0, 0, 0);
    acc1 = __builtin_amdgcn_mfma_f32_32x32x16_bf16(v10, pf0, acc1, 0, 0, 0);
    acc1 = __builtin_amdgcn_mfma_f32_32x32x16_bf16(v11, pf1, acc1, 0, 0, 0);
  }

  // one cross-half reduce for the denominator (was per-iteration)
  l += __shfl_xor(l, 32);

  // ---- key-split merge: fixed M -> pure sums, no rescale ----
  if (half) {
#pragma unroll
    for (int r = 0; r < 16; ++r) {
      OO[qw][lane][r] = acc0[r];
      OO[qw][lane][16 + r] = acc1[r];
    }
    LL[qw][lane] = l;
  }
  __syncthreads();
  if (!half) {
    const float inv = 1.f / (l + LL[qw][lane]);
    // epilogue: acc reg r -> d = nb*32 + 8*(r>>2) + 4*hi + (r&3), q = l31
    unsigned short* ob = O + (size_t)(b * SEQ + q0 + l31) * DMODEL + h * HDIM;
#pragma unroll
    for (int g = 0; g < 4; ++g) {
      float e00 = (acc0[4 * g]     + OO[qw][lane][4 * g])     * inv;
      float e01 = (acc0[4 * g + 1] + OO[qw][lane][4 * g + 1]) * inv;
      float e02 = (acc0[4 * g + 2] + OO[qw][lane][4 * g + 2]) * inv;
      float e03 = (acc0[4 * g + 3] + OO[qw][lane][4 * g + 3]) * inv;
      float e10 = (acc1[4 * g]     + OO[qw][lane][16 + 4 * g])     * inv;
      float e11 = (acc1[4 * g + 1] + OO[qw][lane][16 + 4 * g + 1]) * inv;
      float e12 = (acc1[4 * g + 2] + OO[qw][lane][16 + 4 * g + 2]) * inv;
      float e13 = (acc1[4 * g + 3] + OO[qw][lane][16 + 4 * g + 3]) * inv;
      s16x4 o0 = { (short)f2bf(e00), (short)f2bf(e01), (short)f2bf(e02), (short)f2bf(e03) };
      s16x4 o1 = { (short)f2bf(e10), (short)f2bf(e11), (short)f2bf(e12), (short)f2bf(e13) };
      *(s16x4*)(ob + g * 8 + hi * 4) = o0;
      *(s16x4*)(ob + 32 + g * 8 + hi * 4) = o1;
    }
  }
}

// ---------------------------------------------------------------------------
// launch: ws layout (bytes): Wq[0,6M) Wo[6M,8M) Xb[8M,16M) QKV[16M,40M) Vt[40M,48M)
// ---------------------------------------------------------------------------
extern "C" void kernel_launch(void* const* d_in, const int* in_sizes, int n_in,
                              void* d_out, int out_size, void* d_ws, size_t ws_size,
                              hipStream_t stream) {
  const float* x    = (const float*)d_in[0];
  const float* wqkv = (const float*)d_in[1];
  const float* wout = (const float*)d_in[2];
  char* ws = (char*)d_ws;
  unsigned short* Wq  = (unsigned short*)(ws);
  unsigned short* Wo  = (unsigned short*)(ws + 6291456);
  unsigned short* Xb  = (unsigned short*)(ws + 8388608);
  unsigned short* QKV = (unsigned short*)(ws + 16777216);
  unsigned short* Vt  = (unsigned short*)(ws + 41943040);
  (void)in_sizes; (void)n_in; (void)out_size; (void)ws_size;

  k_wnorm<<<QKVC, 256, 0, stream>>>(wqkv, Wq);
  k_wnorm<<<DMODEL, 256, 0, stream>>>(wout, Wo);
  k_cast<<<(NROWS * DMODEL) / 1024, 256, 0, stream>>>(x, Xb);
  k_gemm_bt<1><<<(NROWS / 128) * (QKVC / 128), 256, 0, stream>>>(
      Xb, Wq, (void*)QKV, NROWS, QKVC, DMODEL);
  k_qknorm<<<NROWS, 256, 0, stream>>>(QKV);
  k_vtrans<<<BATCH * NHEAD * (SEQ / 64), 256, 0, stream>>>(QKV, Vt);
  k_attn<<<BATCH * NHEAD * 16, 512, 0, stream>>>(QKV, Vt, Xb);
  k_gemm_bt<0><<<(NROWS / 128) * (DMODEL / 128), 256, 0, stream>>>(
      Xb, Wo, d_out, NROWS, DMODEL, DMODEL);
}

// Round 11
// 144.714 us; speedup vs baseline: 2.8010x; 1.4501x over previous
//
#include <hip/hip_runtime.h>

// ---------------- fixed problem shape ----------------
#define BATCH  2
#define SEQ    2048
#define DMODEL 1024
#define NHEAD  16
#define HDIM   64
#define NROWS  (BATCH * SEQ)   // 4096
#define QKVC   (3 * DMODEL)    // 3072

typedef float f32x4 __attribute__((ext_vector_type(4)));
typedef float f32x16 __attribute__((ext_vector_type(16)));
typedef short s16x8 __attribute__((ext_vector_type(8)));
typedef short s16x4 __attribute__((ext_vector_type(4)));
typedef unsigned int u32x4 __attribute__((ext_vector_type(4)));

__device__ __forceinline__ unsigned short f2bf(float f) {
  unsigned int u = __float_as_uint(f);
  u = (u + 0x7FFFu + ((u >> 16) & 1u)) >> 16;   // RNE
  return (unsigned short)u;
}
__device__ __forceinline__ float bf2f(unsigned short s) {
  return __uint_as_float(((unsigned int)s) << 16);
}
// pack two f32 -> two bf16 in one u32 (low = a, high = b)
__device__ __forceinline__ unsigned pkbf(float a, float b) {
  unsigned r;
  asm("v_cvt_pk_bf16_f32 %0, %1, %2" : "=v"(r) : "v"(a), "v"(b));
  return r;
}
// v_permlane32_swap_b32 DST, SRC: DST[32:63] <-> SRC[0:31]
// SAFE only with two genuinely distinct values (R7 lesson).
__device__ __forceinline__ void swp(unsigned &a, unsigned &b) {
  asm volatile("v_permlane32_swap_b32 %0, %1" : "+v"(a), "+v"(b));
}

// ---------------------------------------------------------------------------
// 1) row-normalize f32 weight rows (len 1024) -> bf16
// ---------------------------------------------------------------------------
__global__ __launch_bounds__(256) void k_wnorm(const float* __restrict__ W,
                                               unsigned short* __restrict__ Wh) {
  const int row = blockIdx.x, tid = threadIdx.x;
  const float4* rp = (const float4*)(W + (size_t)row * DMODEL);
  float4 v = rp[tid];
  float ss = v.x * v.x + v.y * v.y + v.z * v.z + v.w * v.w;
#pragma unroll
  for (int m = 1; m < 64; m <<= 1) ss += __shfl_xor(ss, m);
  __shared__ float part[4];
  if ((tid & 63) == 0) part[tid >> 6] = ss;
  __syncthreads();
  const float tot = part[0] + part[1] + part[2] + part[3];
  const float scale = 0.03125f / (1e-4f + sqrtf(tot) * 0.03125f);
  unsigned short* op = Wh + (size_t)row * DMODEL + tid * 4;
  op[0] = f2bf(v.x * scale); op[1] = f2bf(v.y * scale);
  op[2] = f2bf(v.z * scale); op[3] = f2bf(v.w * scale);
}

// ---------------------------------------------------------------------------
// 2) f32 -> bf16 cast
// ---------------------------------------------------------------------------
__global__ __launch_bounds__(256) void k_cast(const float* __restrict__ X,
                                              unsigned short* __restrict__ Xb) {
  const int i = blockIdx.x * 256 + threadIdx.x;
  const float4 v = ((const float4*)X)[i];
  ushort4 o = { f2bf(v.x), f2bf(v.y), f2bf(v.z), f2bf(v.w) };
  ((ushort4*)Xb)[i] = o;
}

// ---------------------------------------------------------------------------
// 3) C[M][N] = A[M][K] * B[N][K]^T  (unchanged)
// ---------------------------------------------------------------------------
#define LDP 88
template <int WRITE_BF16>
__global__ __launch_bounds__(256) void k_gemm_bt(const unsigned short* __restrict__ A,
                                                 const unsigned short* __restrict__ Bm,
                                                 void* __restrict__ Cv,
                                                 int M, int N, int K) {
  __shared__ unsigned short As[128 * LDP];
  __shared__ unsigned short Bs[128 * LDP];
  const int tid = threadIdx.x;
  const int nbn = N >> 7;
  const int bm = (blockIdx.x / nbn) << 7;
  const int bn = (blockIdx.x % nbn) << 7;
  const int wave = tid >> 6, lane = tid & 63;
  const int wr = (wave >> 1) << 6, wc = (wave & 1) << 6;
  const int l16 = lane & 15, lg = lane >> 4;

  f32x4 acc[4][4];
#pragma unroll
  for (int m = 0; m < 4; ++m)
#pragma unroll
    for (int n = 0; n < 4; ++n) acc[m][n] = (f32x4){0.f, 0.f, 0.f, 0.f};

  for (int k0 = 0; k0 < K; k0 += 64) {
    s16x8 ra[4], rb[4];
#pragma unroll
    for (int it = 0; it < 4; ++it) {
      const int c = it * 256 + tid;
      const int r = c >> 3, col = (c & 7) << 3;
      ra[it] = *(const s16x8*)(A + (size_t)(bm + r) * K + k0 + col);
      rb[it] = *(const s16x8*)(Bm + (size_t)(bn + r) * K + k0 + col);
    }
    __syncthreads();
#pragma unroll
    for (int it = 0; it < 4; ++it) {
      const int c = it * 256 + tid;
      const int r = c >> 3, col = (c & 7) << 3;
      *(s16x8*)(As + r * LDP + col) = ra[it];
      *(s16x8*)(Bs + r * LDP + col) = rb[it];
    }
    __syncthreads();
#pragma unroll
    for (int ks = 0; ks < 2; ++ks) {
      s16x8 af[4], bq[4];
#pragma unroll
      for (int m = 0; m < 4; ++m)
        af[m] = *(const s16x8*)(As + (wr + m * 16 + l16) * LDP + ks * 32 + lg * 8);
#pragma unroll
      for (int n = 0; n < 4; ++n)
        bq[n] = *(const s16x8*)(Bs + (wc + n * 16 + l16) * LDP + ks * 32 + lg * 8);
#pragma unroll
      for (int m = 0; m < 4; ++m)
#pragma unroll
        for (int n = 0; n < 4; ++n)
          acc[m][n] = __builtin_amdgcn_mfma_f32_16x16x32_bf16(af[m], bq[n], acc[m][n], 0, 0, 0);
    }
  }
  if (WRITE_BF16) {
    unsigned short* C = (unsigned short*)Cv;
#pragma unroll
    for (int m = 0; m < 4; ++m)
#pragma unroll
      for (int n = 0; n < 4; ++n)
#pragma unroll
        for (int r = 0; r < 4; ++r)
          C[(size_t)(bm + wr + m * 16 + lg * 4 + r) * N + (bn + wc + n * 16 + l16)] =
              f2bf(acc[m][n][r]);
  } else {
    float* C = (float*)Cv;
#pragma unroll
    for (int m = 0; m < 4; ++m)
#pragma unroll
      for (int n = 0; n < 4; ++n)
#pragma unroll
        for (int r = 0; r < 4; ++r)
          C[(size_t)(bm + wr + m * 16 + lg * 4 + r) * N + (bn + wc + n * 16 + l16)] =
              acc[m][n][r];
  }
}

// ---------------------------------------------------------------------------
// 4) normalize q,k head-vectors in-place; q rows fold attn scale 1/8
// ---------------------------------------------------------------------------
__global__ __launch_bounds__(256) void k_qknorm(unsigned short* __restrict__ qkv) {
  const int row = blockIdx.x, tid = threadIdx.x;
  const int hv = tid >> 3, g = tid & 7;
  const int base = (hv < 16) ? (hv * HDIM) : (DMODEL + (hv - 16) * HDIM);
  unsigned short* p = qkv + (size_t)row * QKVC + base + g * 8;
  s16x8 v = *(const s16x8*)p;
  float f[8];
  float ss = 0.f;
#pragma unroll
  for (int j = 0; j < 8; ++j) { f[j] = bf2f((unsigned short)v[j]); ss += f[j] * f[j]; }
  ss += __shfl_xor(ss, 1); ss += __shfl_xor(ss, 2); ss += __shfl_xor(ss, 4);
  float scale = 1.f / (1e-4f + sqrtf(ss) * 0.125f);
  if (hv < 16) scale *= 0.125f;
  s16x8 o;
#pragma unroll
  for (int j = 0; j < 8; ++j) o[j] = (short)f2bf(f[j] * scale);
  *(s16x8*)p = o;
}

// ---------------------------------------------------------------------------
// 5) V transpose: qkv v-part -> Vt[bh][d][t]
// ---------------------------------------------------------------------------
__global__ __launch_bounds__(256) void k_vtrans(const unsigned short* __restrict__ qkv,
                                                unsigned short* __restrict__ Vt) {
  const int tt = blockIdx.x & 31, bh = blockIdx.x >> 5;
  const int b = bh >> 4, h = bh & 15;
  const int t0 = tt * 64;
  __shared__ unsigned short tile[64][80];
  const int tid = threadIdx.x;
#pragma unroll
  for (int half = 0; half < 2; ++half) {
    const int tl = half * 32 + (tid >> 3), part = tid & 7;
    s16x8 v = *(const s16x8*)(qkv + (size_t)(b * SEQ + t0 + tl) * QKVC + 2 * DMODEL +
                              h * HDIM + part * 8);
    *(s16x8*)(&tile[tl][part * 8]) = v;
  }
  __syncthreads();
#pragma unroll
  for (int half = 0; half < 2; ++half) {
    const int d = half * 32 + (tid >> 3), tp = tid & 7;
    s16x8 o;
#pragma unroll
    for (int j = 0; j < 8; ++j) o[j] = (short)tile[tp * 8 + j][d];
    *(s16x8*)(Vt + (size_t)(bh * HDIM + d) * SEQ + t0 + tp * 8) = o;
  }
}

// ---------------------------------------------------------------------------
// 6) flash attention, R11: COOPERATIVE LDS-STAGED K/V (m214 structure).
//    4 waves / 128 queries per block, all 2048 keys (no key-split/merge).
//    Per 64-key tile: block stages K[64 keys][64 d] and Vt[64 d][64 keys]
//    as [row][8 x 16B-chunk] with chunk ^= (row&7) XOR swizzle (T2), via
//    fully-coalesced 128B row-segments (2 x 16B loads/thread per matrix).
//    Fragments read by ds_read_b128 with the same XOR. Fixed-max softmax
//    (R10-verified) + in-register repack (R8-verified). 2-barrier/tile.
// ---------------------------------------------------------------------------
__global__ __launch_bounds__(256) void k_attn(const unsigned short* __restrict__ qkv,
                                              const unsigned short* __restrict__ Vt,
                                              unsigned short* __restrict__ O) {
  const int bid = blockIdx.x;
  const int logical = ((bid & 7) << 6) + (bid >> 3);   // XCD clustering (512%8==0)
  const int bh = logical >> 4, qt = logical & 15;
  const int b = bh >> 4, h = bh & 15;
  const int tid = threadIdx.x;
  const int wave = tid >> 6, lane = tid & 63;
  const int l31 = lane & 31, hi = lane >> 5;
  const int q0 = qt * 128 + wave * 32;

  __shared__ s16x8 ks[64 * 8];   // [key][chunk^], 8KB
  __shared__ s16x8 vs[64 * 8];   // [d][chunk^],   8KB

  // Q B-fragments (col=q=l31, k=8*hi+j), 1/8 scale pre-folded
  const unsigned short* qp =
      qkv + (size_t)(b * SEQ + q0 + l31) * QKVC + h * HDIM + hi * 8;
  const s16x8 qf0 = *(const s16x8*)(qp);
  const s16x8 qf1 = *(const s16x8*)(qp + 16);
  const s16x8 qf2 = *(const s16x8*)(qp + 32);
  const s16x8 qf3 = *(const s16x8*)(qp + 48);

  // staging geometry: thread -> (row = tid>>3 and +32, chunk = tid&7)
  const int srow = tid >> 3, chunk = tid & 7;
  const unsigned short* ksrc =
      qkv + (size_t)(b * SEQ + srow) * QKVC + DMODEL + h * HDIM + chunk * 8;
  const unsigned short* vsrc =
      Vt + (size_t)(bh * HDIM + srow) * SEQ + chunk * 8;
  const int wsl = srow * 8 + (chunk ^ (srow & 7));     // (srow+32)&7 == srow&7
  const int wsh = wsl + 32 * 8;

  f32x16 acc0 = {0,0,0,0,0,0,0,0,0,0,0,0,0,0,0,0};
  f32x16 acc1 = {0,0,0,0,0,0,0,0,0,0,0,0,0,0,0,0};
  float l = 0.f;

  for (int kt = 0; kt < SEQ; kt += 64) {
    // ---- issue coalesced staging loads early (hide under prev compute) ----
    const s16x8 rk0 = *(const s16x8*)(ksrc + (size_t)kt * QKVC);
    const s16x8 rk1 = *(const s16x8*)(ksrc + (size_t)(kt + 32) * QKVC);
    const s16x8 rv0 = *(const s16x8*)(vsrc + kt);
    const s16x8 rv1 = *(const s16x8*)(vsrc + (size_t)32 * SEQ + kt);
    __syncthreads();                 // previous tile fully consumed
    ks[wsl] = rk0; ks[wsh] = rk1;
    vs[wsl] = rv0; vs[wsh] = rv1;
    __syncthreads();                 // staged tile visible
#pragma unroll
    for (int kh = 0; kh < 2; ++kh) {
      const int key = kh * 32 + l31;
      const int kb = key * 8, kx = key & 7;
      // ---- S^T: QK over 4 k-steps (chunk = 2s+hi, XOR kx) ----
      f32x16 st = {0,0,0,0,0,0,0,0,0,0,0,0,0,0,0,0};
      st = __builtin_amdgcn_mfma_f32_32x32x16_bf16(ks[kb + ((0 + hi) ^ kx)], qf0, st, 0, 0, 0);
      st = __builtin_amdgcn_mfma_f32_32x32x16_bf16(ks[kb + ((2 + hi) ^ kx)], qf1, st, 0, 0, 0);
      st = __builtin_amdgcn_mfma_f32_32x32x16_bf16(ks[kb + ((4 + hi) ^ kx)], qf2, st, 0, 0, 0);
      st = __builtin_amdgcn_mfma_f32_32x32x16_bf16(ks[kb + ((6 + hi) ^ kx)], qf3, st, 0, 0, 0);

      // ---- P = exp(S - 8), exact (|S| <= 8 by construction, R10) ----
#pragma unroll
      for (int r = 0; r < 16; ++r) st[r] = __expf(st[r] - 8.f);

      // ---- in-lane denominator ----
      float s0 = (st[0] + st[1]) + (st[2] + st[3]);
      float s1 = (st[4] + st[5]) + (st[6] + st[7]);
      float s2 = (st[8] + st[9]) + (st[10] + st[11]);
      float s3 = (st[12] + st[13]) + (st[14] + st[15]);
      l += (s0 + s1) + (s2 + s3);

      // ---- repack P -> B-fragments (R8-verified) ----
      unsigned P0 = pkbf(st[0], st[1]),   P1 = pkbf(st[2], st[3]);
      unsigned P2 = pkbf(st[4], st[5]),   P3 = pkbf(st[6], st[7]);
      unsigned P4 = pkbf(st[8], st[9]),   P5 = pkbf(st[10], st[11]);
      unsigned P6 = pkbf(st[12], st[13]), P7 = pkbf(st[14], st[15]);
      swp(P0, P2);
      swp(P1, P3);
      swp(P4, P6);
      swp(P5, P7);
      u32x4 w0; w0[0] = P0; w0[1] = P1; w0[2] = P2; w0[3] = P3;
      u32x4 w1; w1[0] = P4; w1[1] = P5; w1[2] = P6; w1[3] = P7;
      const s16x8 pf0 = __builtin_bit_cast(s16x8, w0);
      const s16x8 pf1 = __builtin_bit_cast(s16x8, w1);

      // ---- O^T += V^T * P^T (V chunk = kh*4 + 2s' + hi, XOR d&7) ----
      const int vb0 = l31 * 8,        vx0 = l31 & 7;
      const int vb1 = (l31 + 32) * 8, vx1 = vx0;      // (l31+32)&7 == l31&7
      acc0 = __builtin_amdgcn_mfma_f32_32x32x16_bf16(vs[vb0 + ((kh * 4 + 0 + hi) ^ vx0)], pf0, acc0, 0, 0, 0);
      acc0 = __builtin_amdgcn_mfma_f32_32x32x16_bf16(vs[vb0 + ((kh * 4 + 2 + hi) ^ vx0)], pf1, acc0, 0, 0, 0);
      acc1 = __builtin_amdgcn_mfma_f32_32x32x16_bf16(vs[vb1 + ((kh * 4 + 0 + hi) ^ vx1)], pf0, acc1, 0, 0, 0);
      acc1 = __builtin_amdgcn_mfma_f32_32x32x16_bf16(vs[vb1 + ((kh * 4 + 2 + hi) ^ vx1)], pf1, acc1, 0, 0, 0);
    }
  }

  // one cross-half reduce for the denominator
  l += __shfl_xor(l, 32);

  // ---- epilogue (R8-verified): reg r -> d = nb*32 + 8*(r>>2) + 4*hi + (r&3) ----
  const float inv = 1.f / l;
  unsigned short* ob = O + (size_t)(b * SEQ + q0 + l31) * DMODEL + h * HDIM;
#pragma unroll
  for (int g = 0; g < 4; ++g) {
    s16x4 o0 = { (short)f2bf(acc0[4 * g] * inv),     (short)f2bf(acc0[4 * g + 1] * inv),
                 (short)f2bf(acc0[4 * g + 2] * inv), (short)f2bf(acc0[4 * g + 3] * inv) };
    s16x4 o1 = { (short)f2bf(acc1[4 * g] * inv),     (short)f2bf(acc1[4 * g + 1] * inv),
                 (short)f2bf(acc1[4 * g + 2] * inv), (short)f2bf(acc1[4 * g + 3] * inv) };
    *(s16x4*)(ob + g * 8 + hi * 4) = o0;
    *(s16x4*)(ob + 32 + g * 8 + hi * 4) = o1;
  }
}

// ---------------------------------------------------------------------------
// launch: ws layout (bytes): Wq[0,6M) Wo[6M,8M) Xb[8M,16M) QKV[16M,40M) Vt[40M,48M)
// ---------------------------------------------------------------------------
extern "C" void kernel_launch(void* const* d_in, const int* in_sizes, int n_in,
                              void* d_out, int out_size, void* d_ws, size_t ws_size,
                              hipStream_t stream) {
  const float* x    = (const float*)d_in[0];
  const float* wqkv = (const float*)d_in[1];
  const float* wout = (const float*)d_in[2];
  char* ws = (char*)d_ws;
  unsigned short* Wq  = (unsigned short*)(ws);
  unsigned short* Wo  = (unsigned short*)(ws + 6291456);
  unsigned short* Xb  = (unsigned short*)(ws + 8388608);
  unsigned short* QKV = (unsigned short*)(ws + 16777216);
  unsigned short* Vt  = (unsigned short*)(ws + 41943040);
  (void)in_sizes; (void)n_in; (void)out_size; (void)ws_size;

  k_wnorm<<<QKVC, 256, 0, stream>>>(wqkv, Wq);
  k_wnorm<<<DMODEL, 256, 0, stream>>>(wout, Wo);
  k_cast<<<(NROWS * DMODEL) / 1024, 256, 0, stream>>>(x, Xb);
  k_gemm_bt<1><<<(NROWS / 128) * (QKVC / 128), 256, 0, stream>>>(
      Xb, Wq, (void*)QKV, NROWS, QKVC, DMODEL);
  k_qknorm<<<NROWS, 256, 0, stream>>>(QKV);
  k_vtrans<<<BATCH * NHEAD * (SEQ / 64), 256, 0, stream>>>(QKV, Vt);
  k_attn<<<BATCH * NHEAD * 16, 256, 0, stream>>>(QKV, Vt, Xb);
  k_gemm_bt<0><<<(NROWS / 128) * (DMODEL / 128), 256, 0, stream>>>(
      Xb, Wo, d_out, NROWS, DMODEL, DMODEL);
}